// Round 4
// baseline (462.290 us; speedup 1.0000x reference)
//
#include <hip/hip_runtime.h>
#include <hip/hip_bf16.h>

#define B_  4
#define L_  2048
#define D_  512
#define H_  8
#define HD_ 64
#define M_  (B_ * L_)   // 8192

typedef __bf16 bf16;
typedef __attribute__((ext_vector_type(8)))  __bf16 bf16x8;
typedef __attribute__((ext_vector_type(4)))  __bf16 bf16x4;
typedef __attribute__((ext_vector_type(16))) float  f32x16;

__device__ __forceinline__ f32x16 mfma32(bf16x8 a, bf16x8 b, f32x16 c) {
    return __builtin_amdgcn_mfma_f32_32x32x16_bf16(a, b, c, 0, 0, 0);
}

// ---- pack: src fp32 [R][512] -> dst bf16 panels [64][R][8] ----
__device__ __forceinline__ void pack_body(const float* __restrict__ src,
                                          bf16* __restrict__ dst, int R,
                                          int m0, int k0)
{
    __shared__ __align__(16) bf16 tile[64][76];
    const int t = threadIdx.x;
#pragma unroll
    for (int rep = 0; rep < 4; rep++) {
        const int idx = rep * 256 + t;
        const int r = idx >> 4, c4 = idx & 15;
        const float4 f = *(const float4*)(src + (size_t)(m0 + r) * 512 + k0 + c4 * 4);
        bf16x4 v; v[0] = (bf16)f.x; v[1] = (bf16)f.y; v[2] = (bf16)f.z; v[3] = (bf16)f.w;
        *(bf16x4*)(&tile[r][c4 * 4]) = v;
    }
    __syncthreads();
#pragma unroll
    for (int rep = 0; rep < 2; rep++) {
        const int s = rep * 256 + t;
        const int ml = s & 63, kpl = s >> 6;
        const bf16x4 lo = *(const bf16x4*)(&tile[ml][kpl * 8]);
        const bf16x4 hi4 = *(const bf16x4*)(&tile[ml][kpl * 8 + 4]);
        bf16x8 v;
#pragma unroll
        for (int e = 0; e < 4; e++) { v[e] = lo[e]; v[e + 4] = hi4[e]; }
        *(bf16x8*)(dst + ((size_t)(k0 / 8 + kpl) * R + m0 + ml) * 8) = v;
    }
}

// z<4: weight z (blockIdx.x<8); z=4: q->P0; z=5: k->P1; z=6: v->P2.
// grid (128, 8, 7), block 256.
__global__ __launch_bounds__(256) void pack_all(
    const float* __restrict__ q, const float* __restrict__ k,
    const float* __restrict__ v,
    const float* __restrict__ W0, const float* __restrict__ W1,
    const float* __restrict__ W2, const float* __restrict__ W3,
    bf16* __restrict__ Wp, bf16* __restrict__ P0, bf16* __restrict__ P1,
    bf16* __restrict__ P2)
{
    const int z = blockIdx.z;
    if (z < 4) {
        if (blockIdx.x >= 8) return;
        const float* src = z == 0 ? W0 : z == 1 ? W1 : z == 2 ? W2 : W3;
        pack_body(src, Wp + (size_t)z * 64 * 512 * 8, 512, blockIdx.x * 64, blockIdx.y * 64);
    } else {
        const float* src = z == 4 ? q : z == 5 ? k : v;
        bf16* dst = z == 4 ? P0 : z == 5 ? P1 : P2;
        pack_body(src, dst, M_, blockIdx.x * 64, blockIdx.y * 64);
    }
}

// ---- projection: relu(Xp @ Wp^T + b) (*postmul) ----
// Panel inputs.  Block 256/4 waves, tile 128m x 64n, k-step 64, single
// LDS dbuf (1 barrier/k-step) + THREE register prefetch sets.
// grid (64, 8, NZ), NZ up to 3 independent jobs.  mode 0: bf16 [B,H,L,HD];
// 1: K-panels [BH][8][L][8]; 2: fp32 [M,512]; 3: V-panels [BH][256][64][8]
// PI-swizzled.
struct PJob {
    const bf16* X; const bf16* W; const float* bias; void* out;
    float postmul; int mode;
};

__global__ __launch_bounds__(256, 3) void proj_kernel(PJob j0, PJob j1, PJob j2)
{
    const PJob jb = (blockIdx.z == 0) ? j0 : (blockIdx.z == 1) ? j1 : j2;
    const int w    = threadIdx.x >> 6;
    const int lane = threadIdx.x & 63;
    const int l31  = lane & 31;
    const int hi   = lane >> 5;
    const int m0 = blockIdx.x * 128;
    const int n0 = blockIdx.y * 64;
    const int mh = w & 1;
    const int nh = w >> 1;

    __shared__ __align__(16) bf16 Ab[2][16][64][8];   // 32 KB
    __shared__ __align__(16) bf16 Bb[2][8][64][8];    // 16 KB

    f32x16 acc[2];
#pragma unroll
    for (int mi = 0; mi < 2; mi++)
#pragma unroll
        for (int r = 0; r < 16; r++) acc[mi][r] = 0.0f;

    auto ldA = [&](int f, int k0) -> bf16x8 {
        return *(const bf16x8*)(jb.X + ((size_t)((k0 >> 3) + (f >> 2) * 2 + hi) * M_
                                        + m0 + (f & 3) * 32 + l31) * 8);
    };
    auto ldB = [&](int f, int k0) -> bf16x8 {
        return *(const bf16x8*)(jb.W + ((size_t)((k0 >> 3) + (f >> 1) * 2 + hi) * 512
                                        + n0 + (f & 1) * 32 + l31) * 8);
    };

    bf16x8 rA[3][4], rB[3][2];
#pragma unroll
    for (int i = 0; i < 4; i++) rA[0][i] = ldA(w * 4 + i, 0);
#pragma unroll
    for (int i = 0; i < 2; i++) rB[0][i] = ldB(w * 2 + i, 0);
#pragma unroll
    for (int i = 0; i < 4; i++) *(bf16x8*)(&Ab[0][w * 4 + i][lane][0]) = rA[0][i];
#pragma unroll
    for (int i = 0; i < 2; i++) *(bf16x8*)(&Bb[0][w * 2 + i][lane][0]) = rB[0][i];
#pragma unroll
    for (int s = 1; s < 3; s++) {
#pragma unroll
        for (int i = 0; i < 4; i++) rA[s][i] = ldA(w * 4 + i, s * 64);
#pragma unroll
        for (int i = 0; i < 2; i++) rB[s][i] = ldB(w * 2 + i, s * 64);
    }
    __syncthreads();

#pragma unroll
    for (int it = 0; it < 8; it++) {
        const int cur = it & 1;
        if (it < 5) {
            const int s = it % 3, kn = (it + 3) * 64;
#pragma unroll
            for (int i = 0; i < 4; i++) rA[s][i] = ldA(w * 4 + i, kn);
#pragma unroll
            for (int i = 0; i < 2; i++) rB[s][i] = ldB(w * 2 + i, kn);
        }
#pragma unroll
        for (int ks = 0; ks < 4; ks++) {
            const bf16x8 bfr = *(const bf16x8*)(&Bb[cur][ks * 2 + nh][lane][0]);
#pragma unroll
            for (int mi = 0; mi < 2; mi++) {
                const bf16x8 afr = *(const bf16x8*)(&Ab[cur][ks * 4 + mh * 2 + mi][lane][0]);
                acc[mi] = mfma32(afr, bfr, acc[mi]);
            }
        }
        if (it < 7) {
            const int s = (it + 1) % 3;
#pragma unroll
            for (int i = 0; i < 4; i++) *(bf16x8*)(&Ab[1 - cur][w * 4 + i][lane][0]) = rA[s][i];
#pragma unroll
            for (int i = 0; i < 2; i++) *(bf16x8*)(&Bb[1 - cur][w * 2 + i][lane][0]) = rB[s][i];
            __syncthreads();
        }
    }

    const int col = n0 + nh * 32 + l31;
    const float bn = jb.bias[col];
    const int mode = jb.mode;
#pragma unroll
    for (int mi = 0; mi < 2; mi++)
#pragma unroll
        for (int r = 0; r < 16; r++) {
            const int row = m0 + (mh * 2 + mi) * 32 + (r & 3) + 8 * (r >> 2) + 4 * hi;
            float v = fmaxf(acc[mi][r] + bn, 0.0f);
            if (mode == 2) {
                ((float*)jb.out)[(size_t)row * D_ + col] = v;
            } else {
                v *= jb.postmul;
                const int b = row >> 11, l = row & (L_ - 1);
                const int h = col >> 6,  hd = col & (HD_ - 1);
                const int bh = b * H_ + h;
                size_t idx;
                if (mode == 0) {
                    idx = ((size_t)bh * L_ + l) * HD_ + hd;
                } else if (mode == 1) {       // K panels [bh][hd>>3][l][hd&7]
                    idx = (((size_t)bh * 8 + (hd >> 3)) * L_ + l) * 8 + (hd & 7);
                } else {                      // mode 3: V panels, PI-swizzled j
                    const int swzl = (l & ~15) | (l & 3) | ((l & 4) << 1) | ((l & 8) >> 1);
                    idx = (((size_t)bh * 256 + (swzl >> 3)) * 64 + hd) * 8 + (swzl & 7);
                }
                ((bf16*)jb.out)[idx] = (bf16)v;
            }
        }
}

// ---- flash attention, max-free (post-ReLU q,k => scores >= 0) ----
// SPLIT-KV: block 128 = 2 waves on the SAME 32 q-rows; wave w handles KV
// tiles [w*16, w*16+16).  K and V fragments load DIRECTLY global->register
// (panels lane-contiguous, L2-resident per bh via XCD-chunked swizzle).
// Main loop barrier-free; max-free softmax => partials combine by addition.
//
// ROUND-4 register diet (target: 3 waves/SIMD; unified-file total <= 170):
//  * lacc/ones MFMA row-sum REMOVED (-20 regs, -4 MFMA/tile).  Row sums
//    accumulate per-lane in LANE-space (S^T: lane=q, reg=k): scalar
//    ls += tree-sum(exp2(s[r])).  End-of-kernel: one __shfl_xor(32) folds
//    the hi k-half, then 16 lane-broadcast __shfl's transpose q from
//    lane-space to the reg-space of the o accumulators.
//  * QK cluster SPLIT: compute s0, finish half 0 (s0 dies), compute s1,
//    finish half 1 -> s0/s1 never co-live (-16 regs).  Prefetch points:
//    vf[0..3] refill after PV half 0, kr refill after QK-s1, vf[4..7]
//    refill after PV half 1.
//  * __launch_bounds__(128, 3): allocator budget 170 VGPR (round 2 proved
//    (128,4)'s 64-reg budget spills catastrophically; demand here ~165).
//  * Combine LDS transposed to [16][64] (round-3's [64][16] f32x16 layout
//    was a 32-way bank conflict: 884k conflict cycles).
__global__ __launch_bounds__(128, 3) void attn_kernel(
    const bf16* __restrict__ qh, const bf16* __restrict__ Kp,
    const bf16* __restrict__ Vp, bf16* __restrict__ Op)
{
    const int w    = threadIdx.x >> 6;   // 0..1 : KV half
    const int lane = threadIdx.x & 63;
    const int l31  = lane & 31;
    const int hi   = lane >> 5;
    const int tw   = w * 16;             // first tile of this wave's half

    const int lin  = blockIdx.x + (blockIdx.y << 6);   // dispatch-linear id
    const int xcd  = lin & 7;
    const int slot = lin >> 3;                          // 0..255 within XCD
    const int bh   = (xcd << 2) + (slot >> 6);          // 4 bh per XCD
    const int qb   = (slot & 63) << 5;                  // 64 q-blocks of 32

    const bf16* Q   = qh + (size_t)bh * L_ * HD_;
    const bf16* Kpb = Kp + (size_t)bh * 8 * L_ * 8;
    const bf16* Vpb = Vp + (size_t)bh * 256 * 64 * 8;

    __shared__ float smo[2][16][64];   // 8 KB combine (conflict-free)
    __shared__ float sml[64];

    bf16x8 qf[4];
#pragma unroll
    for (int ks = 0; ks < 4; ks++)
        qf[ks] = *(const bf16x8*)(Q + (size_t)(qb + l31) * HD_ + ks * 16 + hi * 8);

    f32x16 zz;
#pragma unroll
    for (int r = 0; r < 16; r++) zz[r] = 0.0f;
    f32x16 o0 = zz, o1 = zz;
    float ls = 0.0f;

    auto ldK = [&](int f, int t) -> bf16x8 {   // f: ks=f>>1, jt=f&1
        return *(const bf16x8*)(Kpb + ((size_t)((f >> 1) * 2 + hi) * L_
                                       + t * 64 + (f & 1) * 32 + l31) * 8);
    };
    auto ldV = [&](int f, int t) -> bf16x8 {   // f: ksj=f>>1, hdf=f&1
        return *(const bf16x8*)(Vpb + ((size_t)(t * 8 + (f >> 1) * 2 + hi) * 64
                                       + (f & 1) * 32 + l31) * 8);
    };

    bf16x8 kr[8], vf[8];
#pragma unroll
    for (int f = 0; f < 8; f++) kr[f] = ldK(f, tw);
#pragma unroll
    for (int f = 0; f < 8; f++) vf[f] = ldV(f, tw);

#pragma unroll 2
    for (int tt = 0; tt < 16; tt++) {
        const int t = tw + tt;

        // ---- QK half 0: s0 = K[evens] @ Q^T ----
        __builtin_amdgcn_s_setprio(1);
        f32x16 s0 = mfma32(kr[0], qf[0], zz);
#pragma unroll
        for (int ks = 1; ks < 4; ks++) s0 = mfma32(kr[ks * 2], qf[ks], s0);
        __builtin_amdgcn_s_setprio(0);

        // exp2 -> row-sum tree (lane-space) -> pack -> PV half 0
#pragma unroll
        for (int r = 0; r < 16; r++) s0[r] = __builtin_amdgcn_exp2f(s0[r]);
        {
            float a0 = (s0[0] + s0[1]) + (s0[2] + s0[3]);
            float a1 = (s0[4] + s0[5]) + (s0[6] + s0[7]);
            float a2 = (s0[8] + s0[9]) + (s0[10] + s0[11]);
            float a3 = (s0[12] + s0[13]) + (s0[14] + s0[15]);
            ls += (a0 + a1) + (a2 + a3);
        }
        bf16x8 pf0, pf1;
#pragma unroll
        for (int u = 0; u < 8; u++) { pf0[u] = (bf16)s0[u]; pf1[u] = (bf16)s0[8 + u]; }
        __builtin_amdgcn_s_setprio(1);
        o0 = mfma32(pf0, vf[0], o0);
        o1 = mfma32(pf0, vf[1], o1);
        o0 = mfma32(pf1, vf[2], o0);
        o1 = mfma32(pf1, vf[3], o1);
        __builtin_amdgcn_s_setprio(0);
        if (tt < 15) {               // refill vf[0..3] for t+1
#pragma unroll
            for (int f = 0; f < 4; f++) vf[f] = ldV(f, t + 1);
        }

        // ---- QK half 1: s1 = K[odds] @ Q^T (s0/pf0/pf1 now dead) ----
        __builtin_amdgcn_s_setprio(1);
        f32x16 s1 = mfma32(kr[1], qf[0], zz);
#pragma unroll
        for (int ks = 1; ks < 4; ks++) s1 = mfma32(kr[ks * 2 + 1], qf[ks], s1);
        __builtin_amdgcn_s_setprio(0);
        if (tt < 15) {               // refill K for t+1 (next use: QK-s0 of t+1)
#pragma unroll
            for (int f = 0; f < 8; f++) kr[f] = ldK(f, t + 1);
        }

#pragma unroll
        for (int r = 0; r < 16; r++) s1[r] = __builtin_amdgcn_exp2f(s1[r]);
        {
            float a0 = (s1[0] + s1[1]) + (s1[2] + s1[3]);
            float a1 = (s1[4] + s1[5]) + (s1[6] + s1[7]);
            float a2 = (s1[8] + s1[9]) + (s1[10] + s1[11]);
            float a3 = (s1[12] + s1[13]) + (s1[14] + s1[15]);
            ls += (a0 + a1) + (a2 + a3);
        }
        bf16x8 pf2, pf3;
#pragma unroll
        for (int u = 0; u < 8; u++) { pf2[u] = (bf16)s1[u]; pf3[u] = (bf16)s1[8 + u]; }
        __builtin_amdgcn_s_setprio(1);
        o0 = mfma32(pf2, vf[4], o0);
        o1 = mfma32(pf2, vf[5], o1);
        o0 = mfma32(pf3, vf[6], o0);
        o1 = mfma32(pf3, vf[7], o1);
        __builtin_amdgcn_s_setprio(0);
        if (tt < 15) {               // refill vf[4..7]
#pragma unroll
            for (int f = 4; f < 8; f++) vf[f] = ldV(f, t + 1);
        }
    }

    // ---- combine the two KV halves (pure addition: max-free softmax) ----
    if (w == 1) {
#pragma unroll
        for (int r = 0; r < 16; r++) {
            smo[0][r][lane] = o0[r];
            smo[1][r][lane] = o1[r];
        }
        sml[lane] = ls;
    }
    __syncthreads();
    if (w == 1) return;
#pragma unroll
    for (int r = 0; r < 16; r++) {
        o0[r] += smo[0][r][lane];
        o1[r] += smo[1][r][lane];
    }
    ls += sml[lane];

    // Fold the hi k-half, then broadcast lane-space sums to reg-space rows.
    const float lst = ls + __shfl_xor(ls, 32);

    const int b = bh >> 3, h = bh & 7;
#pragma unroll
    for (int r = 0; r < 16; r++) {
        const int rl = (r & 3) + 8 * (r >> 2) + 4 * hi;   // this reg's q-row
        const float inv = 1.0f / __shfl(lst, rl);
        const int m = b * L_ + qb + rl;
        const int c0 = h * HD_ + l31;
        Op[((size_t)(c0 >> 3) * M_ + m) * 8 + (c0 & 7)] = (bf16)(o0[r] * inv);
        const int c1 = c0 + 32;
        Op[((size_t)(c1 >> 3) * M_ + m) * 8 + (c1 & 7)] = (bf16)(o1[r] * inv);
    }
}

extern "C" void kernel_launch(void* const* d_in, const int* in_sizes, int n_in,
                              void* d_out, int out_size, void* d_ws, size_t ws_size,
                              hipStream_t stream)
{
    (void)in_sizes; (void)n_in; (void)out_size;
    const float* q  = (const float*)d_in[0];
    const float* k  = (const float*)d_in[1];
    const float* v  = (const float*)d_in[2];
    const float* Wq = (const float*)d_in[3];
    const float* bq = (const float*)d_in[4];
    const float* Wk = (const float*)d_in[5];
    const float* bk = (const float*)d_in[6];
    const float* Wv = (const float*)d_in[7];
    const float* bv = (const float*)d_in[8];
    const float* Wo = (const float*)d_in[9];
    const float* bo = (const float*)d_in[10];
    float* out = (float*)d_out;

    // ws: P0 @0, P1 @8M, P2 @16M, Wp @24M (2 MB), [VpN @26M if room].
    // d_out (16 MB): qh @0, Kp @8M -- both dead before the final projection.
    // Fallback (ws < 34MB): Vp overwrites P0 (needs serialized proj_v).
    // Op overwrites P1 (Xk dead after the q/k/v projections).
    char* ws = (char*)d_ws;
    const size_t MB = 1024 * 1024;
    bf16* P0  = (bf16*)(ws);
    bf16* P1  = (bf16*)(ws + 8 * MB);
    bf16* P2  = (bf16*)(ws + 16 * MB);
    bf16* Wp  = (bf16*)(ws + 24 * MB);
    bf16* qh  = (bf16*)(d_out);
    bf16* Kp  = (bf16*)((char*)d_out + 8 * MB);
    bf16* Opb = P1;

    bf16* Wqp = Wp;
    bf16* Wkp = Wp + (size_t)64 * 512 * 8;
    bf16* Wvp = Wp + (size_t)2 * 64 * 512 * 8;
    bf16* Wop = Wp + (size_t)3 * 64 * 512 * 8;

    const float SCALE_LOG2E = 0.06377946282349575f;  // (1/sqrt(512))*log2(e)

    dim3 pb(256);
    pack_all<<<dim3(128, 8, 7), pb, 0, stream>>>(q, k, v, Wq, Wk, Wv, Wo,
                                                 Wp, P0, P1, P2);

    if (ws_size >= (size_t)34 * MB) {
        // Merged path: all three projections in one launch (independent
        // outputs; Vp gets fresh workspace so it doesn't alias Xq=P0).
        bf16* VpN = (bf16*)(ws + 26 * MB);
        PJob jq{P0, Wqp, bq, qh,  SCALE_LOG2E, 0};
        PJob jk{P1, Wkp, bk, Kp,  1.0f, 1};
        PJob jv{P2, Wvp, bv, VpN, 1.0f, 3};
        proj_kernel<<<dim3(64, 8, 3), pb, 0, stream>>>(jq, jk, jv);

        attn_kernel<<<dim3(64, 32), dim3(128), 0, stream>>>(qh, Kp, VpN, Opb);
    } else {
        bf16* Vp = P0;
        PJob jq{P0, Wqp, bq, qh, SCALE_LOG2E, 0};
        PJob jk{P1, Wkp, bk, Kp, 1.0f, 1};
        proj_kernel<<<dim3(64, 8, 2), pb, 0, stream>>>(jq, jk, jk);

        PJob jv{P2, Wvp, bv, Vp, 1.0f, 3};
        proj_kernel<<<dim3(64, 8, 1), pb, 0, stream>>>(jv, jv, jv);

        attn_kernel<<<dim3(64, 32), dim3(128), 0, stream>>>(qh, Kp, Vp, Opb);
    }

    PJob jo{Opb, Wop, bo, out, 1.0f, 2};
    proj_kernel<<<dim3(64, 8, 1), pb, 0, stream>>>(jo, jo, jo);
}

// Round 5
// 368.700 us; speedup vs baseline: 1.2538x; 1.2538x over previous
//
#include <hip/hip_runtime.h>
#include <hip/hip_bf16.h>

#define B_  4
#define L_  2048
#define D_  512
#define H_  8
#define HD_ 64
#define M_  (B_ * L_)   // 8192

typedef __bf16 bf16;
typedef __attribute__((ext_vector_type(8)))  __bf16 bf16x8;
typedef __attribute__((ext_vector_type(4)))  __bf16 bf16x4;
typedef __attribute__((ext_vector_type(16))) float  f32x16;

__device__ __forceinline__ f32x16 mfma32(bf16x8 a, bf16x8 b, f32x16 c) {
    return __builtin_amdgcn_mfma_f32_32x32x16_bf16(a, b, c, 0, 0, 0);
}

// ---- pack: src fp32 [R][512] -> dst bf16 panels [64][R][8] ----
__device__ __forceinline__ void pack_body(const float* __restrict__ src,
                                          bf16* __restrict__ dst, int R,
                                          int m0, int k0)
{
    __shared__ __align__(16) bf16 tile[64][76];
    const int t = threadIdx.x;
#pragma unroll
    for (int rep = 0; rep < 4; rep++) {
        const int idx = rep * 256 + t;
        const int r = idx >> 4, c4 = idx & 15;
        const float4 f = *(const float4*)(src + (size_t)(m0 + r) * 512 + k0 + c4 * 4);
        bf16x4 v; v[0] = (bf16)f.x; v[1] = (bf16)f.y; v[2] = (bf16)f.z; v[3] = (bf16)f.w;
        *(bf16x4*)(&tile[r][c4 * 4]) = v;
    }
    __syncthreads();
#pragma unroll
    for (int rep = 0; rep < 2; rep++) {
        const int s = rep * 256 + t;
        const int ml = s & 63, kpl = s >> 6;
        const bf16x4 lo = *(const bf16x4*)(&tile[ml][kpl * 8]);
        const bf16x4 hi4 = *(const bf16x4*)(&tile[ml][kpl * 8 + 4]);
        bf16x8 v;
#pragma unroll
        for (int e = 0; e < 4; e++) { v[e] = lo[e]; v[e + 4] = hi4[e]; }
        *(bf16x8*)(dst + ((size_t)(k0 / 8 + kpl) * R + m0 + ml) * 8) = v;
    }
}

// z<4: weight z (blockIdx.x<8); z=4: q->P0; z=5: k->P1; z=6: v->P2.
// grid (128, 8, 7), block 256.
__global__ __launch_bounds__(256) void pack_all(
    const float* __restrict__ q, const float* __restrict__ k,
    const float* __restrict__ v,
    const float* __restrict__ W0, const float* __restrict__ W1,
    const float* __restrict__ W2, const float* __restrict__ W3,
    bf16* __restrict__ Wp, bf16* __restrict__ P0, bf16* __restrict__ P1,
    bf16* __restrict__ P2)
{
    const int z = blockIdx.z;
    if (z < 4) {
        if (blockIdx.x >= 8) return;
        const float* src = z == 0 ? W0 : z == 1 ? W1 : z == 2 ? W2 : W3;
        pack_body(src, Wp + (size_t)z * 64 * 512 * 8, 512, blockIdx.x * 64, blockIdx.y * 64);
    } else {
        const float* src = z == 4 ? q : z == 5 ? k : v;
        bf16* dst = z == 4 ? P0 : z == 5 ? P1 : P2;
        pack_body(src, dst, M_, blockIdx.x * 64, blockIdx.y * 64);
    }
}

// ---- projection: relu(Xp @ Wp^T + b) (*postmul) ----
// Panel inputs.  Block 256/4 waves, tile 128m x 64n, k-step 64, single
// LDS dbuf (1 barrier/k-step) + THREE register prefetch sets.
// grid (64, 8, NZ), NZ up to 3 independent jobs.  mode 0: bf16 [B,H,L,HD];
// 1: K-panels [BH][8][L][8]; 2: fp32 [M,512]; 3: V-panels [BH][256][64][8]
// PI-swizzled.
struct PJob {
    const bf16* X; const bf16* W; const float* bias; void* out;
    float postmul; int mode;
};

__global__ __launch_bounds__(256, 3) void proj_kernel(PJob j0, PJob j1, PJob j2)
{
    const PJob jb = (blockIdx.z == 0) ? j0 : (blockIdx.z == 1) ? j1 : j2;
    const int w    = threadIdx.x >> 6;
    const int lane = threadIdx.x & 63;
    const int l31  = lane & 31;
    const int hi   = lane >> 5;
    const int m0 = blockIdx.x * 128;
    const int n0 = blockIdx.y * 64;
    const int mh = w & 1;
    const int nh = w >> 1;

    __shared__ __align__(16) bf16 Ab[2][16][64][8];   // 32 KB
    __shared__ __align__(16) bf16 Bb[2][8][64][8];    // 16 KB

    f32x16 acc[2];
#pragma unroll
    for (int mi = 0; mi < 2; mi++)
#pragma unroll
        for (int r = 0; r < 16; r++) acc[mi][r] = 0.0f;

    auto ldA = [&](int f, int k0) -> bf16x8 {
        return *(const bf16x8*)(jb.X + ((size_t)((k0 >> 3) + (f >> 2) * 2 + hi) * M_
                                        + m0 + (f & 3) * 32 + l31) * 8);
    };
    auto ldB = [&](int f, int k0) -> bf16x8 {
        return *(const bf16x8*)(jb.W + ((size_t)((k0 >> 3) + (f >> 1) * 2 + hi) * 512
                                        + n0 + (f & 1) * 32 + l31) * 8);
    };

    bf16x8 rA[3][4], rB[3][2];
#pragma unroll
    for (int i = 0; i < 4; i++) rA[0][i] = ldA(w * 4 + i, 0);
#pragma unroll
    for (int i = 0; i < 2; i++) rB[0][i] = ldB(w * 2 + i, 0);
#pragma unroll
    for (int i = 0; i < 4; i++) *(bf16x8*)(&Ab[0][w * 4 + i][lane][0]) = rA[0][i];
#pragma unroll
    for (int i = 0; i < 2; i++) *(bf16x8*)(&Bb[0][w * 2 + i][lane][0]) = rB[0][i];
#pragma unroll
    for (int s = 1; s < 3; s++) {
#pragma unroll
        for (int i = 0; i < 4; i++) rA[s][i] = ldA(w * 4 + i, s * 64);
#pragma unroll
        for (int i = 0; i < 2; i++) rB[s][i] = ldB(w * 2 + i, s * 64);
    }
    __syncthreads();

#pragma unroll
    for (int it = 0; it < 8; it++) {
        const int cur = it & 1;
        if (it < 5) {
            const int s = it % 3, kn = (it + 3) * 64;
#pragma unroll
            for (int i = 0; i < 4; i++) rA[s][i] = ldA(w * 4 + i, kn);
#pragma unroll
            for (int i = 0; i < 2; i++) rB[s][i] = ldB(w * 2 + i, kn);
        }
#pragma unroll
        for (int ks = 0; ks < 4; ks++) {
            const bf16x8 bfr = *(const bf16x8*)(&Bb[cur][ks * 2 + nh][lane][0]);
#pragma unroll
            for (int mi = 0; mi < 2; mi++) {
                const bf16x8 afr = *(const bf16x8*)(&Ab[cur][ks * 4 + mh * 2 + mi][lane][0]);
                acc[mi] = mfma32(afr, bfr, acc[mi]);
            }
        }
        if (it < 7) {
            const int s = (it + 1) % 3;
#pragma unroll
            for (int i = 0; i < 4; i++) *(bf16x8*)(&Ab[1 - cur][w * 4 + i][lane][0]) = rA[s][i];
#pragma unroll
            for (int i = 0; i < 2; i++) *(bf16x8*)(&Bb[1 - cur][w * 2 + i][lane][0]) = rB[s][i];
            __syncthreads();
        }
    }

    const int col = n0 + nh * 32 + l31;
    const float bn = jb.bias[col];
    const int mode = jb.mode;
#pragma unroll
    for (int mi = 0; mi < 2; mi++)
#pragma unroll
        for (int r = 0; r < 16; r++) {
            const int row = m0 + (mh * 2 + mi) * 32 + (r & 3) + 8 * (r >> 2) + 4 * hi;
            float v = fmaxf(acc[mi][r] + bn, 0.0f);
            if (mode == 2) {
                ((float*)jb.out)[(size_t)row * D_ + col] = v;
            } else {
                v *= jb.postmul;
                const int b = row >> 11, l = row & (L_ - 1);
                const int h = col >> 6,  hd = col & (HD_ - 1);
                const int bh = b * H_ + h;
                size_t idx;
                if (mode == 0) {
                    idx = ((size_t)bh * L_ + l) * HD_ + hd;
                } else if (mode == 1) {       // K panels [bh][hd>>3][l][hd&7]
                    idx = (((size_t)bh * 8 + (hd >> 3)) * L_ + l) * 8 + (hd & 7);
                } else {                      // mode 3: V panels, PI-swizzled j
                    const int swzl = (l & ~15) | (l & 3) | ((l & 4) << 1) | ((l & 8) >> 1);
                    idx = (((size_t)bh * 256 + (swzl >> 3)) * 64 + hd) * 8 + (swzl & 7);
                }
                ((bf16*)jb.out)[idx] = (bf16)v;
            }
        }
}

// ---- flash attention, max-free (post-ReLU q,k => scores >= 0) ----
// ROUND-5: barrier-free 1-wave blocks (round-1 structure, proven no-spill
// at 116 VGPR under (64,2)) + DEPENDENCY-CHAIN SPLITTING.  Occupancy is
// pinned at 2 waves/SIMD by the reg-class quantization (steps at 128/256
// total regs; this kernel's ~200-reg state can't reach the 128 class --
// rounds 2-4 proved forcing it spills catastrophically).  So instead of
// TLP, raise intra-wave MFMA ILP:
//  * QK: each s-half computed as TWO independent depth-2 partial chains
//    (t0+t1 / t2+t3, merged by 16 VALU adds) instead of one depth-4 chain.
//  * PV: persistent accumulators split o0->o0a+o0b, o1->o1a+o1b (merged
//    once at epilogue) -> four independent depth-2 chains per tile.
//  * Row-sums in lane-space (round-4's verified trick): no lacc/ones
//    MFMAs (16 MFMA issue/tile instead of 20); transpose to reg-space at
//    the epilogue via one __shfl_xor + per-reg __shfl broadcast.
// K and V fragments load DIRECTLY global->register (panels lane-contig,
// L2-resident per bh via XCD-chunked swizzle).  No LDS, no __syncthreads.
// Grid (64,32) = 2048 blocks x 1 wave = 2 waves/SIMD.
__global__ __launch_bounds__(64, 2) void attn_kernel(
    const bf16* __restrict__ qh, const bf16* __restrict__ Kp,
    const bf16* __restrict__ Vp, bf16* __restrict__ Op)
{
    const int lane = threadIdx.x;
    const int l31  = lane & 31;
    const int hi   = lane >> 5;

    const int lin  = blockIdx.x + (blockIdx.y << 6);   // dispatch-linear id
    const int xcd  = lin & 7;
    const int slot = lin >> 3;                          // 0..255 within XCD
    const int bh   = (xcd << 2) + (slot >> 6);          // 4 bh per XCD
    const int qb   = (slot & 63) << 5;                  // 64 q-blocks of 32

    const bf16* Q   = qh + (size_t)bh * L_ * HD_;
    const bf16* Kpb = Kp + (size_t)bh * 8 * L_ * 8;
    const bf16* Vpb = Vp + (size_t)bh * 256 * 64 * 8;

    bf16x8 qf[4];
#pragma unroll
    for (int ks = 0; ks < 4; ks++)
        qf[ks] = *(const bf16x8*)(Q + (size_t)(qb + l31) * HD_ + ks * 16 + hi * 8);

    f32x16 zz;
#pragma unroll
    for (int r = 0; r < 16; r++) zz[r] = 0.0f;
    f32x16 o0a = zz, o0b = zz, o1a = zz, o1b = zz;
    float ls = 0.0f;

    auto ldK = [&](int f, int t) -> bf16x8 {   // f: ks=f>>1, jt=f&1
        return *(const bf16x8*)(Kpb + ((size_t)((f >> 1) * 2 + hi) * L_
                                       + t * 64 + (f & 1) * 32 + l31) * 8);
    };
    auto ldV = [&](int f, int t) -> bf16x8 {   // f: ksj=f>>1, hdf=f&1
        return *(const bf16x8*)(Vpb + ((size_t)(t * 8 + (f >> 1) * 2 + hi) * 64
                                       + (f & 1) * 32 + l31) * 8);
    };

    bf16x8 kr[8], vf[8];
#pragma unroll
    for (int f = 0; f < 8; f++) kr[f] = ldK(f, 0);
#pragma unroll
    for (int f = 0; f < 8; f++) vf[f] = ldV(f, 0);

#pragma unroll 2
    for (int t = 0; t < 32; t++) {
        // ---- QK: 4 independent depth-2 chains (was 2 depth-4) ----
        __builtin_amdgcn_s_setprio(1);
        f32x16 t0 = mfma32(kr[0], qf[0], zz);   // s0 partial a (j-half 0)
        f32x16 t1 = mfma32(kr[4], qf[2], zz);   // s0 partial b
        f32x16 t2 = mfma32(kr[1], qf[0], zz);   // s1 partial a (j-half 1)
        f32x16 t3 = mfma32(kr[5], qf[2], zz);   // s1 partial b
        t0 = mfma32(kr[2], qf[1], t0);
        t1 = mfma32(kr[6], qf[3], t1);
        t2 = mfma32(kr[3], qf[1], t2);
        t3 = mfma32(kr[7], qf[3], t3);
        __builtin_amdgcn_s_setprio(0);
        if (t < 31) {                // refill K for t+1 (kr fully consumed)
#pragma unroll
            for (int f = 0; f < 8; f++) kr[f] = ldK(f, t + 1);
        }

        // ---- half 0: merge -> exp2 -> rowsum (lane-space) -> pack -> PV ----
        f32x16 s0;
#pragma unroll
        for (int r = 0; r < 16; r++)
            s0[r] = __builtin_amdgcn_exp2f(t0[r] + t1[r]);
        {
            float a0 = (s0[0] + s0[1]) + (s0[2] + s0[3]);
            float a1 = (s0[4] + s0[5]) + (s0[6] + s0[7]);
            float a2 = (s0[8] + s0[9]) + (s0[10] + s0[11]);
            float a3 = (s0[12] + s0[13]) + (s0[14] + s0[15]);
            ls += (a0 + a1) + (a2 + a3);
        }
        bf16x8 pf0, pf1;
#pragma unroll
        for (int u = 0; u < 8; u++) { pf0[u] = (bf16)s0[u]; pf1[u] = (bf16)s0[8 + u]; }
        __builtin_amdgcn_s_setprio(1);
        o0a = mfma32(pf0, vf[0], o0a);   // 4 independent chains
        o1a = mfma32(pf0, vf[1], o1a);
        o0b = mfma32(pf1, vf[2], o0b);
        o1b = mfma32(pf1, vf[3], o1b);
        __builtin_amdgcn_s_setprio(0);
        if (t < 31) {                // refill vf[0..3] for t+1
#pragma unroll
            for (int f = 0; f < 4; f++) vf[f] = ldV(f, t + 1);
        }

        // ---- half 1 ----
        f32x16 s1;
#pragma unroll
        for (int r = 0; r < 16; r++)
            s1[r] = __builtin_amdgcn_exp2f(t2[r] + t3[r]);
        {
            float a0 = (s1[0] + s1[1]) + (s1[2] + s1[3]);
            float a1 = (s1[4] + s1[5]) + (s1[6] + s1[7]);
            float a2 = (s1[8] + s1[9]) + (s1[10] + s1[11]);
            float a3 = (s1[12] + s1[13]) + (s1[14] + s1[15]);
            ls += (a0 + a1) + (a2 + a3);
        }
        bf16x8 pf2, pf3;
#pragma unroll
        for (int u = 0; u < 8; u++) { pf2[u] = (bf16)s1[u]; pf3[u] = (bf16)s1[8 + u]; }
        __builtin_amdgcn_s_setprio(1);
        o0a = mfma32(pf2, vf[4], o0a);
        o1a = mfma32(pf2, vf[5], o1a);
        o0b = mfma32(pf3, vf[6], o0b);
        o1b = mfma32(pf3, vf[7], o1b);
        __builtin_amdgcn_s_setprio(0);
        if (t < 31) {                // refill vf[4..7]
#pragma unroll
            for (int f = 4; f < 8; f++) vf[f] = ldV(f, t + 1);
        }
    }

    // ---- epilogue: merge accumulator halves, normalize, store ----
    // Fold the hi k-half of the lane-space sums, then broadcast to reg-space.
    const float lst = ls + __shfl_xor(ls, 32);

    const int b = bh >> 3, h = bh & 7;
#pragma unroll
    for (int r = 0; r < 16; r++) {
        const int rl = (r & 3) + 8 * (r >> 2) + 4 * hi;   // this reg's q-row
        const float inv = 1.0f / __shfl(lst, rl);
        const int m = b * L_ + qb + rl;
        const int c0 = h * HD_ + l31;
        Op[((size_t)(c0 >> 3) * M_ + m) * 8 + (c0 & 7)] = (bf16)((o0a[r] + o0b[r]) * inv);
        const int c1 = c0 + 32;
        Op[((size_t)(c1 >> 3) * M_ + m) * 8 + (c1 & 7)] = (bf16)((o1a[r] + o1b[r]) * inv);
    }
}

extern "C" void kernel_launch(void* const* d_in, const int* in_sizes, int n_in,
                              void* d_out, int out_size, void* d_ws, size_t ws_size,
                              hipStream_t stream)
{
    (void)in_sizes; (void)n_in; (void)out_size;
    const float* q  = (const float*)d_in[0];
    const float* k  = (const float*)d_in[1];
    const float* v  = (const float*)d_in[2];
    const float* Wq = (const float*)d_in[3];
    const float* bq = (const float*)d_in[4];
    const float* Wk = (const float*)d_in[5];
    const float* bk = (const float*)d_in[6];
    const float* Wv = (const float*)d_in[7];
    const float* bv = (const float*)d_in[8];
    const float* Wo = (const float*)d_in[9];
    const float* bo = (const float*)d_in[10];
    float* out = (float*)d_out;

    // ws: P0 @0, P1 @8M, P2 @16M, Wp @24M (2 MB), [VpN @26M if room].
    // d_out (16 MB): qh @0, Kp @8M -- both dead before the final projection.
    // Fallback (ws < 34MB): Vp overwrites P0 (needs serialized proj_v).
    // Op overwrites P1 (Xk dead after the q/k/v projections).
    char* ws = (char*)d_ws;
    const size_t MB = 1024 * 1024;
    bf16* P0  = (bf16*)(ws);
    bf16* P1  = (bf16*)(ws + 8 * MB);
    bf16* P2  = (bf16*)(ws + 16 * MB);
    bf16* Wp  = (bf16*)(ws + 24 * MB);
    bf16* qh  = (bf16*)(d_out);
    bf16* Kp  = (bf16*)((char*)d_out + 8 * MB);
    bf16* Opb = P1;

    bf16* Wqp = Wp;
    bf16* Wkp = Wp + (size_t)64 * 512 * 8;
    bf16* Wvp = Wp + (size_t)2 * 64 * 512 * 8;
    bf16* Wop = Wp + (size_t)3 * 64 * 512 * 8;

    const float SCALE_LOG2E = 0.06377946282349575f;  // (1/sqrt(512))*log2(e)

    dim3 pb(256);
    pack_all<<<dim3(128, 8, 7), pb, 0, stream>>>(q, k, v, Wq, Wk, Wv, Wo,
                                                 Wp, P0, P1, P2);

    if (ws_size >= (size_t)34 * MB) {
        // Merged path: all three projections in one launch (independent
        // outputs; Vp gets fresh workspace so it doesn't alias Xq=P0).
        bf16* VpN = (bf16*)(ws + 26 * MB);
        PJob jq{P0, Wqp, bq, qh,  SCALE_LOG2E, 0};
        PJob jk{P1, Wkp, bk, Kp,  1.0f, 1};
        PJob jv{P2, Wvp, bv, VpN, 1.0f, 3};
        proj_kernel<<<dim3(64, 8, 3), pb, 0, stream>>>(jq, jk, jv);

        attn_kernel<<<dim3(64, 32), dim3(64), 0, stream>>>(qh, Kp, VpN, Opb);
    } else {
        bf16* Vp = P0;
        PJob jq{P0, Wqp, bq, qh, SCALE_LOG2E, 0};
        PJob jk{P1, Wkp, bk, Kp, 1.0f, 1};
        proj_kernel<<<dim3(64, 8, 2), pb, 0, stream>>>(jq, jk, jk);

        PJob jv{P2, Wvp, bv, Vp, 1.0f, 3};
        proj_kernel<<<dim3(64, 8, 1), pb, 0, stream>>>(jv, jv, jv);

        attn_kernel<<<dim3(64, 32), dim3(64), 0, stream>>>(qh, Kp, Vp, Opb);
    }

    PJob jo{Opb, Wop, bo, out, 1.0f, 2};
    proj_kernel<<<dim3(64, 8, 1), pb, 0, stream>>>(jo, jo, jo);
}

// Round 6
// 217.798 us; speedup vs baseline: 2.1226x; 1.6929x over previous
//
#include <hip/hip_runtime.h>
#include <hip/hip_bf16.h>

#define B_  4
#define L_  2048
#define D_  512
#define H_  8
#define HD_ 64
#define M_  (B_ * L_)   // 8192

typedef __bf16 bf16;
typedef __attribute__((ext_vector_type(8)))  __bf16 bf16x8;
typedef __attribute__((ext_vector_type(4)))  __bf16 bf16x4;
typedef __attribute__((ext_vector_type(16))) float  f32x16;

__device__ __forceinline__ f32x16 mfma32(bf16x8 a, bf16x8 b, f32x16 c) {
    return __builtin_amdgcn_mfma_f32_32x32x16_bf16(a, b, c, 0, 0, 0);
}

// ---- pack: src fp32 [R][512] -> dst bf16 panels [64][R][8] ----
__device__ __forceinline__ void pack_body(const float* __restrict__ src,
                                          bf16* __restrict__ dst, int R,
                                          int m0, int k0)
{
    __shared__ __align__(16) bf16 tile[64][76];
    const int t = threadIdx.x;
#pragma unroll
    for (int rep = 0; rep < 4; rep++) {
        const int idx = rep * 256 + t;
        const int r = idx >> 4, c4 = idx & 15;
        const float4 f = *(const float4*)(src + (size_t)(m0 + r) * 512 + k0 + c4 * 4);
        bf16x4 v; v[0] = (bf16)f.x; v[1] = (bf16)f.y; v[2] = (bf16)f.z; v[3] = (bf16)f.w;
        *(bf16x4*)(&tile[r][c4 * 4]) = v;
    }
    __syncthreads();
#pragma unroll
    for (int rep = 0; rep < 2; rep++) {
        const int s = rep * 256 + t;
        const int ml = s & 63, kpl = s >> 6;
        const bf16x4 lo = *(const bf16x4*)(&tile[ml][kpl * 8]);
        const bf16x4 hi4 = *(const bf16x4*)(&tile[ml][kpl * 8 + 4]);
        bf16x8 v;
#pragma unroll
        for (int e = 0; e < 4; e++) { v[e] = lo[e]; v[e + 4] = hi4[e]; }
        *(bf16x8*)(dst + ((size_t)(k0 / 8 + kpl) * R + m0 + ml) * 8) = v;
    }
}

// Weights ONLY (q/k/v pack is fused into the projection now).
// grid (8, 8, 4), block 256.
__global__ __launch_bounds__(256) void pack_w(
    const float* __restrict__ W0, const float* __restrict__ W1,
    const float* __restrict__ W2, const float* __restrict__ W3,
    bf16* __restrict__ Wp)
{
    const int z = blockIdx.z;
    const float* src = z == 0 ? W0 : z == 1 ? W1 : z == 2 ? W2 : W3;
    pack_body(src, Wp + (size_t)z * 64 * 512 * 8, 512, blockIdx.x * 64, blockIdx.y * 64);
}

// ---- projection: relu(X @ W^T + b) (*postmul) ----
// Block 256/4 waves, tile 128m x 64n, k-step 64, single LDS dbuf
// (1 barrier/k-step).  B (weights) always bf16 panels, 3-deep register
// prefetch.  A path is templated:
//   FP32A=false: X is bf16 panels [K/8][M][8], 3-deep prefetch (o-proj).
//   FP32A=true : X is raw fp32 [M,512]; 2 float4 loads per fragment,
//                convert->bf16x8 at the LDS store.  2-deep prefetch so the
//                register footprint (~64 regs for rAf) stays within the
//                (256,3) budget of 170 -- rounds 2/4/5 proved overshooting
//                the class boundary spills catastrophically.
// Output modes: 0 bf16 [B,H,L,HD]; 1 K-panels [BH][8][L][8]; 2 fp32
// [M,512]; 3 V-panels [BH][256][64][8] PI-swizzled.
struct PJob {
    const bf16* X; const float* Xf; const bf16* W; const float* bias;
    void* out; float postmul; int mode;
};

template<bool FP32A>
__device__ __forceinline__ void proj_body(const PJob jb)
{
    const int w    = threadIdx.x >> 6;
    const int lane = threadIdx.x & 63;
    const int l31  = lane & 31;
    const int hi   = lane >> 5;
    const int m0 = blockIdx.x * 128;
    const int n0 = blockIdx.y * 64;
    const int mh = w & 1;
    const int nh = w >> 1;

    __shared__ __align__(16) bf16 Ab[2][16][64][8];   // 32 KB
    __shared__ __align__(16) bf16 Bb[2][8][64][8];    // 16 KB

    f32x16 acc[2];
#pragma unroll
    for (int mi = 0; mi < 2; mi++)
#pragma unroll
        for (int r = 0; r < 16; r++) acc[mi][r] = 0.0f;

    auto ldA = [&](int f, int k0) -> bf16x8 {   // panel path
        return *(const bf16x8*)(jb.X + ((size_t)((k0 >> 3) + (f >> 2) * 2 + hi) * M_
                                        + m0 + (f & 3) * 32 + l31) * 8);
    };
    auto ldAf = [&](int f, int k0, float4* d) {  // fp32-direct path
        const int row  = m0 + (f & 3) * 32 + l31;
        const int koct = (k0 >> 3) + (f >> 2) * 2 + hi;
        const float* p = jb.Xf + (size_t)row * 512 + koct * 8;
        d[0] = *(const float4*)p;
        d[1] = *(const float4*)(p + 4);
    };
    auto cv8 = [](const float4* d) -> bf16x8 {
        bf16x8 v;
        v[0] = (bf16)d[0].x; v[1] = (bf16)d[0].y;
        v[2] = (bf16)d[0].z; v[3] = (bf16)d[0].w;
        v[4] = (bf16)d[1].x; v[5] = (bf16)d[1].y;
        v[6] = (bf16)d[1].z; v[7] = (bf16)d[1].w;
        return v;
    };
    auto ldB = [&](int f, int k0) -> bf16x8 {
        return *(const bf16x8*)(jb.W + ((size_t)((k0 >> 3) + (f >> 1) * 2 + hi) * 512
                                        + n0 + (f & 1) * 32 + l31) * 8);
    };

    bf16x8 rA[3][4];        // !FP32A: 3-deep bf16 panel prefetch
    float4 rAf[2][4][2];    //  FP32A: 2-deep fp32 prefetch
    bf16x8 rB[3][2];

    if constexpr (FP32A) {
#pragma unroll
        for (int i = 0; i < 4; i++) ldAf(w * 4 + i, 0, rAf[0][i]);
#pragma unroll
        for (int i = 0; i < 4; i++)
            *(bf16x8*)(&Ab[0][w * 4 + i][lane][0]) = cv8(rAf[0][i]);
#pragma unroll
        for (int i = 0; i < 4; i++) ldAf(w * 4 + i, 64, rAf[1][i]);
    } else {
#pragma unroll
        for (int i = 0; i < 4; i++) rA[0][i] = ldA(w * 4 + i, 0);
#pragma unroll
        for (int i = 0; i < 4; i++)
            *(bf16x8*)(&Ab[0][w * 4 + i][lane][0]) = rA[0][i];
#pragma unroll
        for (int s = 1; s < 3; s++)
#pragma unroll
            for (int i = 0; i < 4; i++) rA[s][i] = ldA(w * 4 + i, s * 64);
    }
#pragma unroll
    for (int i = 0; i < 2; i++) rB[0][i] = ldB(w * 2 + i, 0);
#pragma unroll
    for (int i = 0; i < 2; i++)
        *(bf16x8*)(&Bb[0][w * 2 + i][lane][0]) = rB[0][i];
#pragma unroll
    for (int s = 1; s < 3; s++)
#pragma unroll
        for (int i = 0; i < 2; i++) rB[s][i] = ldB(w * 2 + i, s * 64);
    __syncthreads();

#pragma unroll
    for (int it = 0; it < 8; it++) {
        const int cur = it & 1;
        if constexpr (FP32A) {
            if (it < 6) {
#pragma unroll
                for (int i = 0; i < 4; i++)
                    ldAf(w * 4 + i, (it + 2) * 64, rAf[it & 1][i]);
            }
        } else {
            if (it < 5) {
#pragma unroll
                for (int i = 0; i < 4; i++)
                    rA[it % 3][i] = ldA(w * 4 + i, (it + 3) * 64);
            }
        }
        if (it < 5) {
#pragma unroll
            for (int i = 0; i < 2; i++)
                rB[it % 3][i] = ldB(w * 2 + i, (it + 3) * 64);
        }
#pragma unroll
        for (int ks = 0; ks < 4; ks++) {
            const bf16x8 bfr = *(const bf16x8*)(&Bb[cur][ks * 2 + nh][lane][0]);
#pragma unroll
            for (int mi = 0; mi < 2; mi++) {
                const bf16x8 afr = *(const bf16x8*)(&Ab[cur][ks * 4 + mh * 2 + mi][lane][0]);
                acc[mi] = mfma32(afr, bfr, acc[mi]);
            }
        }
        if (it < 7) {
            if constexpr (FP32A) {
#pragma unroll
                for (int i = 0; i < 4; i++)
                    *(bf16x8*)(&Ab[1 - cur][w * 4 + i][lane][0]) = cv8(rAf[(it + 1) & 1][i]);
            } else {
#pragma unroll
                for (int i = 0; i < 4; i++)
                    *(bf16x8*)(&Ab[1 - cur][w * 4 + i][lane][0]) = rA[(it + 1) % 3][i];
            }
#pragma unroll
            for (int i = 0; i < 2; i++)
                *(bf16x8*)(&Bb[1 - cur][w * 2 + i][lane][0]) = rB[(it + 1) % 3][i];
            __syncthreads();
        }
    }

    const int col = n0 + nh * 32 + l31;
    const float bn = jb.bias[col];
    const int mode = jb.mode;
#pragma unroll
    for (int mi = 0; mi < 2; mi++)
#pragma unroll
        for (int r = 0; r < 16; r++) {
            const int row = m0 + (mh * 2 + mi) * 32 + (r & 3) + 8 * (r >> 2) + 4 * hi;
            float v = fmaxf(acc[mi][r] + bn, 0.0f);
            if (mode == 2) {
                ((float*)jb.out)[(size_t)row * D_ + col] = v;
            } else {
                v *= jb.postmul;
                const int b = row >> 11, l = row & (L_ - 1);
                const int h = col >> 6,  hd = col & (HD_ - 1);
                const int bh = b * H_ + h;
                size_t idx;
                if (mode == 0) {
                    idx = ((size_t)bh * L_ + l) * HD_ + hd;
                } else if (mode == 1) {       // K panels [bh][hd>>3][l][hd&7]
                    idx = (((size_t)bh * 8 + (hd >> 3)) * L_ + l) * 8 + (hd & 7);
                } else {                      // mode 3: V panels, PI-swizzled j
                    const int swzl = (l & ~15) | (l & 3) | ((l & 4) << 1) | ((l & 8) >> 1);
                    idx = (((size_t)bh * 256 + (swzl >> 3)) * 64 + hd) * 8 + (swzl & 7);
                }
                ((bf16*)jb.out)[idx] = (bf16)v;
            }
        }
}

__global__ __launch_bounds__(256, 3) void proj_kernel(PJob j0, PJob j1, PJob j2)
{
    const PJob jb = (blockIdx.z == 0) ? j0 : (blockIdx.z == 1) ? j1 : j2;
    proj_body<false>(jb);
}

__global__ __launch_bounds__(256, 3) void proj_qkv_kernel(PJob j0, PJob j1, PJob j2)
{
    const PJob jb = (blockIdx.z == 0) ? j0 : (blockIdx.z == 1) ? j1 : j2;
    proj_body<true>(jb);
}

// ---- flash attention, max-free (post-ReLU q,k => scores >= 0) ----
// EXACT round-0 structure (best measured: 51.2 us, 100 VGPR, no spill):
// wave=32q, block 2 waves=64q; K fragments direct global->register with
// 1-tile prefetch; V staged via LDS dbuf with 2-tile register prefetch,
// 1 barrier/tile; row-sums via MFMA ones-fragment.  Only change: the
// R1-validated XCD-chunked block swizzle (bijective: 1024 blocks = 8 XCD
// x 4 bh x 32 q-blocks) so each XCD's K+V working set (2 MB) is
// L2-resident -- in R1 this cut FETCH 69.7->12.3 MB.
__global__ __launch_bounds__(128, 2) void attn_kernel(
    const bf16* __restrict__ qh, const bf16* __restrict__ Kp,
    const bf16* __restrict__ Vp, bf16* __restrict__ Op)
{
    const int w    = threadIdx.x >> 6;   // 0..1
    const int lane = threadIdx.x & 63;
    const int l31  = lane & 31;
    const int hi   = lane >> 5;

    const int lin  = blockIdx.x + (blockIdx.y << 5);   // grid (32,32)
    const int xcd  = lin & 7;
    const int slot = lin >> 3;                          // 0..127 within XCD
    const int bh   = (xcd << 2) + (slot >> 5);          // 4 bh per XCD
    const int qb   = (slot & 31) * 64 + w * 32;

    const bf16* Q   = qh + (size_t)bh * L_ * HD_;
    const bf16* Kpb = Kp + (size_t)bh * 8 * L_ * 8;
    const bf16* Vpb = Vp + (size_t)bh * 256 * 64 * 8;

    __shared__ __align__(16) bf16 Vb[2][8][64][8];   // 16 KB

    bf16x8 qf[4];
#pragma unroll
    for (int ks = 0; ks < 4; ks++)
        qf[ks] = *(const bf16x8*)(Q + (size_t)(qb + l31) * HD_ + ks * 16 + hi * 8);

    f32x16 zz;
#pragma unroll
    for (int r = 0; r < 16; r++) zz[r] = 0.0f;
    f32x16 o0 = zz, o1 = zz, lacc = zz;
    bf16x8 ones;
#pragma unroll
    for (int u = 0; u < 8; u++) ones[u] = (bf16)1.0f;

    auto ldK = [&](int f, int t) -> bf16x8 {   // f: ks=f>>1, jt=f&1
        return *(const bf16x8*)(Kpb + ((size_t)((f >> 1) * 2 + hi) * L_
                                       + t * 64 + (f & 1) * 32 + l31) * 8);
    };
    auto ldV = [&](int f, int t) -> bf16x8 {   // f: ksj=f>>1, hdf=f&1
        return *(const bf16x8*)(Vpb + ((size_t)(t * 8 + (f >> 1) * 2 + hi) * 64
                                       + (f & 1) * 32 + l31) * 8);
    };

    bf16x8 kr[8], vr[2][4];
#pragma unroll
    for (int i = 0; i < 4; i++) vr[0][i] = ldV(w * 4 + i, 0);
#pragma unroll
    for (int i = 0; i < 4; i++) *(bf16x8*)(&Vb[0][w * 4 + i][lane][0]) = vr[0][i];
#pragma unroll
    for (int i = 0; i < 4; i++) vr[1][i] = ldV(w * 4 + i, 1);
#pragma unroll
    for (int i = 0; i < 4; i++) vr[0][i] = ldV(w * 4 + i, 2);
#pragma unroll
    for (int f = 0; f < 8; f++) kr[f] = ldK(f, 0);
    __syncthreads();

    auto tile_body = [&](int t, int cur, int nxt) {
        // S^T = K @ Q^T, C-layout; K operands straight from global regs.
        f32x16 s0 = mfma32(kr[0], qf[0], zz);
        f32x16 s1 = mfma32(kr[1], qf[0], zz);
#pragma unroll
        for (int ks = 1; ks < 4; ks++) {
            s0 = mfma32(kr[ks * 2 + 0], qf[ks], s0);
            s1 = mfma32(kr[ks * 2 + 1], qf[ks], s1);
        }
        if (t < 31) {
#pragma unroll
            for (int f = 0; f < 8; f++) kr[f] = ldK(f, t + 1);
        }

        // half 0: exp2 -> P frags (natural order, PI-matched) -> PV + row-sum
#pragma unroll
        for (int r = 0; r < 16; r++) s0[r] = __builtin_amdgcn_exp2f(s0[r]);
        {
            bf16x8 pf0, pf1;
#pragma unroll
            for (int u = 0; u < 8; u++) { pf0[u] = (bf16)s0[u]; pf1[u] = (bf16)s0[8 + u]; }
            o0   = mfma32(pf0, *(const bf16x8*)(&Vb[cur][0][lane][0]), o0);
            o1   = mfma32(pf0, *(const bf16x8*)(&Vb[cur][1][lane][0]), o1);
            lacc = mfma32(pf0, ones, lacc);
            o0   = mfma32(pf1, *(const bf16x8*)(&Vb[cur][2][lane][0]), o0);
            o1   = mfma32(pf1, *(const bf16x8*)(&Vb[cur][3][lane][0]), o1);
            lacc = mfma32(pf1, ones, lacc);
        }
        // half 1
#pragma unroll
        for (int r = 0; r < 16; r++) s1[r] = __builtin_amdgcn_exp2f(s1[r]);
        {
            bf16x8 pf2, pf3;
#pragma unroll
            for (int u = 0; u < 8; u++) { pf2[u] = (bf16)s1[u]; pf3[u] = (bf16)s1[8 + u]; }
            o0   = mfma32(pf2, *(const bf16x8*)(&Vb[cur][4][lane][0]), o0);
            o1   = mfma32(pf2, *(const bf16x8*)(&Vb[cur][5][lane][0]), o1);
            lacc = mfma32(pf2, ones, lacc);
            o0   = mfma32(pf3, *(const bf16x8*)(&Vb[cur][6][lane][0]), o0);
            o1   = mfma32(pf3, *(const bf16x8*)(&Vb[cur][7][lane][0]), o1);
            lacc = mfma32(pf3, ones, lacc);
        }

        if (t < 31) {
            // store tile t+1 (loaded 2 tiles ago), then refill with tile t+3
#pragma unroll
            for (int i = 0; i < 4; i++)
                *(bf16x8*)(&Vb[1 - cur][w * 4 + i][lane][0]) = vr[nxt][i];
            const int tn = (t + 3 < 32) ? t + 3 : 31;
#pragma unroll
            for (int i = 0; i < 4; i++) vr[nxt][i] = ldV(w * 4 + i, tn);
            __syncthreads();
        }
    };

    for (int tt = 0; tt < 16; tt++) {
        tile_body(2 * tt + 0, 0, 1);
        tile_body(2 * tt + 1, 1, 0);
    }

    // Epilogue: lacc rows carry this lane's q-row sums (all n-cols identical).
    const int b = bh >> 3, h = bh & 7;
#pragma unroll
    for (int r = 0; r < 16; r++) {
        const int rl = (r & 3) + 8 * (r >> 2) + 4 * hi;
        const float inv = 1.0f / lacc[r];
        const int m = b * L_ + qb + rl;
        const int c0 = h * HD_ + l31;
        Op[((size_t)(c0 >> 3) * M_ + m) * 8 + (c0 & 7)] = (bf16)(o0[r] * inv);
        const int c1 = c0 + 32;
        Op[((size_t)(c1 >> 3) * M_ + m) * 8 + (c1 & 7)] = (bf16)(o1[r] * inv);
    }
}

extern "C" void kernel_launch(void* const* d_in, const int* in_sizes, int n_in,
                              void* d_out, int out_size, void* d_ws, size_t ws_size,
                              hipStream_t stream)
{
    (void)in_sizes; (void)n_in; (void)out_size; (void)ws_size;
    const float* q  = (const float*)d_in[0];
    const float* k  = (const float*)d_in[1];
    const float* v  = (const float*)d_in[2];
    const float* Wq = (const float*)d_in[3];
    const float* bq = (const float*)d_in[4];
    const float* Wk = (const float*)d_in[5];
    const float* bk = (const float*)d_in[6];
    const float* Wv = (const float*)d_in[7];
    const float* bv = (const float*)d_in[8];
    const float* Wo = (const float*)d_in[9];
    const float* bo = (const float*)d_in[10];
    float* out = (float*)d_out;

    // ws (18 MB): Vp @0 (8M), Opb @8M (8M), Wp @16M (2M).
    // d_out (16 MB): qh @0, Kp @8M -- both dead before the final projection,
    // which overwrites d_out with the fp32 result.
    char* ws = (char*)d_ws;
    const size_t MB = 1024 * 1024;
    bf16* Vp  = (bf16*)(ws);
    bf16* Opb = (bf16*)(ws + 8 * MB);
    bf16* Wp  = (bf16*)(ws + 16 * MB);
    bf16* qh  = (bf16*)(d_out);
    bf16* Kp  = (bf16*)((char*)d_out + 8 * MB);

    bf16* Wqp = Wp;
    bf16* Wkp = Wp + (size_t)64 * 512 * 8;
    bf16* Wvp = Wp + (size_t)2 * 64 * 512 * 8;
    bf16* Wop = Wp + (size_t)3 * 64 * 512 * 8;

    const float SCALE_LOG2E = 0.06377946282349575f;  // (1/sqrt(512))*log2(e)

    pack_w<<<dim3(8, 8, 4), dim3(256), 0, stream>>>(Wq, Wk, Wv, Wo, Wp);

    // All three input projections in ONE launch, reading raw fp32 q/k/v
    // directly (pack fused into the A-path); outputs disjoint.
    PJob jq{nullptr, q, Wqp, bq, qh, SCALE_LOG2E, 0};
    PJob jk{nullptr, k, Wkp, bk, Kp, 1.0f, 1};
    PJob jv{nullptr, v, Wvp, bv, Vp, 1.0f, 3};
    proj_qkv_kernel<<<dim3(64, 8, 3), dim3(256), 0, stream>>>(jq, jk, jv);

    attn_kernel<<<dim3(32, 32), dim3(128), 0, stream>>>(qh, Kp, Vp, Opb);

    PJob jo{Opb, nullptr, Wop, bo, out, 1.0f, 2};
    proj_kernel<<<dim3(64, 8, 1), dim3(256), 0, stream>>>(jo, jo, jo);
}

// Round 7
// 201.655 us; speedup vs baseline: 2.2925x; 1.0801x over previous
//
#include <hip/hip_runtime.h>
#include <hip/hip_bf16.h>

#define B_  4
#define L_  2048
#define D_  512
#define H_  8
#define HD_ 64
#define M_  (B_ * L_)   // 8192

typedef __bf16 bf16;
typedef __attribute__((ext_vector_type(8)))  __bf16 bf16x8;
typedef __attribute__((ext_vector_type(4)))  __bf16 bf16x4;
typedef __attribute__((ext_vector_type(16))) float  f32x16;

__device__ __forceinline__ f32x16 mfma32(bf16x8 a, bf16x8 b, f32x16 c) {
    return __builtin_amdgcn_mfma_f32_32x32x16_bf16(a, b, c, 0, 0, 0);
}

// ---- pack: src fp32 [R][512] -> dst bf16 panels [64][R][8] ----
// Fully coalesced (float4 reads along the row); R6 proved the "fused"
// fp32-direct A path is uncoalesced (2KB lane stride) and latency-bound.
__device__ __forceinline__ void pack_body(const float* __restrict__ src,
                                          bf16* __restrict__ dst, int R,
                                          int m0, int k0)
{
    __shared__ __align__(16) bf16 tile[64][76];
    const int t = threadIdx.x;
#pragma unroll
    for (int rep = 0; rep < 4; rep++) {
        const int idx = rep * 256 + t;
        const int r = idx >> 4, c4 = idx & 15;
        const float4 f = *(const float4*)(src + (size_t)(m0 + r) * 512 + k0 + c4 * 4);
        bf16x4 v; v[0] = (bf16)f.x; v[1] = (bf16)f.y; v[2] = (bf16)f.z; v[3] = (bf16)f.w;
        *(bf16x4*)(&tile[r][c4 * 4]) = v;
    }
    __syncthreads();
#pragma unroll
    for (int rep = 0; rep < 2; rep++) {
        const int s = rep * 256 + t;
        const int ml = s & 63, kpl = s >> 6;
        const bf16x4 lo = *(const bf16x4*)(&tile[ml][kpl * 8]);
        const bf16x4 hi4 = *(const bf16x4*)(&tile[ml][kpl * 8 + 4]);
        bf16x8 v;
#pragma unroll
        for (int e = 0; e < 4; e++) { v[e] = lo[e]; v[e + 4] = hi4[e]; }
        *(bf16x8*)(dst + ((size_t)(k0 / 8 + kpl) * R + m0 + ml) * 8) = v;
    }
}

// z<4: weight z (blockIdx.x<8); z=4: q->P0; z=5: k->P1; z=6: v->P2.
// grid (128, 8, 7), block 256.
__global__ __launch_bounds__(256) void pack_all(
    const float* __restrict__ q, const float* __restrict__ k,
    const float* __restrict__ v,
    const float* __restrict__ W0, const float* __restrict__ W1,
    const float* __restrict__ W2, const float* __restrict__ W3,
    bf16* __restrict__ Wp, bf16* __restrict__ P0, bf16* __restrict__ P1,
    bf16* __restrict__ P2)
{
    const int z = blockIdx.z;
    if (z < 4) {
        if (blockIdx.x >= 8) return;
        const float* src = z == 0 ? W0 : z == 1 ? W1 : z == 2 ? W2 : W3;
        pack_body(src, Wp + (size_t)z * 64 * 512 * 8, 512, blockIdx.x * 64, blockIdx.y * 64);
    } else {
        const float* src = z == 4 ? q : z == 5 ? k : v;
        bf16* dst = z == 4 ? P0 : z == 5 ? P1 : P2;
        pack_body(src, dst, M_, blockIdx.x * 64, blockIdx.y * 64);
    }
}

// ---- projection: relu(Xp @ Wp^T + b) (*postmul) ----
// ROUND-7 rebuild.  R6's profile exposed the old 128x64 structure at 7%
// MfmaUtil (8 MFMA per barrier, latency-bound).  New shape:
//   tile 128m x 128n, k-step 64, block 256 = 4 waves in 2x2.
//   Each wave owns 64x64 = 2x2 32x32 accumulators -> 16 MFMA/wave/barrier,
//   4 independent accumulation chains (ILP 4).
//   LDS: A,B 16 KB per buffer, double-buffered = 64 KB -> 2 blocks/CU.
//   2-deep register prefetch of panel fragments (k_j lives in slot j&1;
//   end of iter it: store k_{it+1}, reload that slot with k_{it+3}).
// Grid per job (64, 4); up to 3 jobs via blockIdx.z.
// Output modes: 0 bf16 [B,H,L,HD]; 1 K-panels [BH][8][L][8]; 2 fp32
// [M,512]; 3 V-panels [BH][256][64][8] PI-swizzled.
struct PJob {
    const bf16* X; const bf16* W; const float* bias; void* out;
    float postmul; int mode;
};

__global__ __launch_bounds__(256, 2) void proj_kernel(PJob j0, PJob j1, PJob j2)
{
    const PJob jb = (blockIdx.z == 0) ? j0 : (blockIdx.z == 1) ? j1 : j2;
    const int w    = threadIdx.x >> 6;
    const int lane = threadIdx.x & 63;
    const int l31  = lane & 31;
    const int hi   = lane >> 5;
    const int m0 = blockIdx.x * 128;
    const int n0 = blockIdx.y * 128;
    const int mh = w & 1;
    const int nh = w >> 1;

    __shared__ __align__(16) bf16 Ab[2][16][64][8];   // 2 x 16 KB
    __shared__ __align__(16) bf16 Bb[2][16][64][8];   // 2 x 16 KB

    f32x16 acc[2][2];
#pragma unroll
    for (int mi = 0; mi < 2; mi++)
#pragma unroll
        for (int ni = 0; ni < 2; ni++)
#pragma unroll
            for (int r = 0; r < 16; r++) acc[mi][ni][r] = 0.0f;

    // fragment f (0..15): koct-pair p=f>>2, sub=f&3.  Wave w stages p=w.
    auto ldA = [&](int f, int k0) -> bf16x8 {
        return *(const bf16x8*)(jb.X + ((size_t)((k0 >> 3) + (f >> 2) * 2 + hi) * M_
                                        + m0 + (f & 3) * 32 + l31) * 8);
    };
    auto ldB = [&](int f, int k0) -> bf16x8 {
        return *(const bf16x8*)(jb.W + ((size_t)((k0 >> 3) + (f >> 2) * 2 + hi) * 512
                                        + n0 + (f & 3) * 32 + l31) * 8);
    };

    bf16x8 rA[2][4], rB[2][4];
    // prologue: k0 -> slot0 -> LDS0; k1 -> slot1; k2 -> slot0 (freed).
#pragma unroll
    for (int i = 0; i < 4; i++) { rA[0][i] = ldA(w * 4 + i, 0);  rB[0][i] = ldB(w * 4 + i, 0); }
#pragma unroll
    for (int i = 0; i < 4; i++) {
        *(bf16x8*)(&Ab[0][w * 4 + i][lane][0]) = rA[0][i];
        *(bf16x8*)(&Bb[0][w * 4 + i][lane][0]) = rB[0][i];
    }
#pragma unroll
    for (int i = 0; i < 4; i++) { rA[1][i] = ldA(w * 4 + i, 64);  rB[1][i] = ldB(w * 4 + i, 64); }
#pragma unroll
    for (int i = 0; i < 4; i++) { rA[0][i] = ldA(w * 4 + i, 128); rB[0][i] = ldB(w * 4 + i, 128); }
    __syncthreads();

#pragma unroll
    for (int it = 0; it < 8; it++) {
        const int cur = it & 1;
#pragma unroll
        for (int ks = 0; ks < 4; ks++) {
            const bf16x8 a0 = *(const bf16x8*)(&Ab[cur][ks * 4 + mh * 2 + 0][lane][0]);
            const bf16x8 a1 = *(const bf16x8*)(&Ab[cur][ks * 4 + mh * 2 + 1][lane][0]);
            const bf16x8 b0 = *(const bf16x8*)(&Bb[cur][ks * 4 + nh * 2 + 0][lane][0]);
            const bf16x8 b1 = *(const bf16x8*)(&Bb[cur][ks * 4 + nh * 2 + 1][lane][0]);
            acc[0][0] = mfma32(a0, b0, acc[0][0]);
            acc[0][1] = mfma32(a0, b1, acc[0][1]);
            acc[1][0] = mfma32(a1, b0, acc[1][0]);
            acc[1][1] = mfma32(a1, b1, acc[1][1]);
        }
        if (it < 7) {
            const int s = (it + 1) & 1;          // slot holding k_{it+1}
#pragma unroll
            for (int i = 0; i < 4; i++) {
                *(bf16x8*)(&Ab[1 - cur][w * 4 + i][lane][0]) = rA[s][i];
                *(bf16x8*)(&Bb[1 - cur][w * 4 + i][lane][0]) = rB[s][i];
            }
            if (it < 5) {                        // refill slot with k_{it+3}
#pragma unroll
                for (int i = 0; i < 4; i++) {
                    rA[s][i] = ldA(w * 4 + i, (it + 3) * 64);
                    rB[s][i] = ldB(w * 4 + i, (it + 3) * 64);
                }
            }
            __syncthreads();
        }
    }

    const int mode = jb.mode;
#pragma unroll
    for (int ni = 0; ni < 2; ni++) {
        const int col = n0 + (nh * 2 + ni) * 32 + l31;
        const float bn = jb.bias[col];
#pragma unroll
        for (int mi = 0; mi < 2; mi++)
#pragma unroll
            for (int r = 0; r < 16; r++) {
                const int row = m0 + (mh * 2 + mi) * 32 + (r & 3) + 8 * (r >> 2) + 4 * hi;
                float v = fmaxf(acc[mi][ni][r] + bn, 0.0f);
                if (mode == 2) {
                    ((float*)jb.out)[(size_t)row * D_ + col] = v;
                } else {
                    v *= jb.postmul;
                    const int b = row >> 11, l = row & (L_ - 1);
                    const int h = col >> 6,  hd = col & (HD_ - 1);
                    const int bh = b * H_ + h;
                    size_t idx;
                    if (mode == 0) {
                        idx = ((size_t)bh * L_ + l) * HD_ + hd;
                    } else if (mode == 1) {       // K panels [bh][hd>>3][l][hd&7]
                        idx = (((size_t)bh * 8 + (hd >> 3)) * L_ + l) * 8 + (hd & 7);
                    } else {                      // mode 3: V panels, PI-swizzled j
                        const int swzl = (l & ~15) | (l & 3) | ((l & 4) << 1) | ((l & 8) >> 1);
                        idx = (((size_t)bh * 256 + (swzl >> 3)) * 64 + hd) * 8 + (swzl & 7);
                    }
                    ((bf16*)jb.out)[idx] = (bf16)v;
                }
            }
    }
}

// ---- flash attention, max-free (post-ReLU q,k => scores >= 0) ----
// EXACT round-0 structure (best measured: 51.2 us, 100 VGPR, no spill):
// wave=32q, block 2 waves=64q; K fragments direct global->register with
// 1-tile prefetch; V staged via LDS dbuf with 2-tile register prefetch,
// 1 barrier/tile; row-sums via MFMA ones-fragment.  Only change: the
// R1-validated XCD-chunked block swizzle (bijective: 1024 blocks = 8 XCD
// x 4 bh x 32 q-blocks) so each XCD's K+V working set (2 MB) is
// L2-resident -- in R1 this cut FETCH 69.7->12.3 MB.
__global__ __launch_bounds__(128, 2) void attn_kernel(
    const bf16* __restrict__ qh, const bf16* __restrict__ Kp,
    const bf16* __restrict__ Vp, bf16* __restrict__ Op)
{
    const int w    = threadIdx.x >> 6;   // 0..1
    const int lane = threadIdx.x & 63;
    const int l31  = lane & 31;
    const int hi   = lane >> 5;

    const int lin  = blockIdx.x + (blockIdx.y << 5);   // grid (32,32)
    const int xcd  = lin & 7;
    const int slot = lin >> 3;                          // 0..127 within XCD
    const int bh   = (xcd << 2) + (slot >> 5);          // 4 bh per XCD
    const int qb   = (slot & 31) * 64 + w * 32;

    const bf16* Q   = qh + (size_t)bh * L_ * HD_;
    const bf16* Kpb = Kp + (size_t)bh * 8 * L_ * 8;
    const bf16* Vpb = Vp + (size_t)bh * 256 * 64 * 8;

    __shared__ __align__(16) bf16 Vb[2][8][64][8];   // 16 KB

    bf16x8 qf[4];
#pragma unroll
    for (int ks = 0; ks < 4; ks++)
        qf[ks] = *(const bf16x8*)(Q + (size_t)(qb + l31) * HD_ + ks * 16 + hi * 8);

    f32x16 zz;
#pragma unroll
    for (int r = 0; r < 16; r++) zz[r] = 0.0f;
    f32x16 o0 = zz, o1 = zz, lacc = zz;
    bf16x8 ones;
#pragma unroll
    for (int u = 0; u < 8; u++) ones[u] = (bf16)1.0f;

    auto ldK = [&](int f, int t) -> bf16x8 {   // f: ks=f>>1, jt=f&1
        return *(const bf16x8*)(Kpb + ((size_t)((f >> 1) * 2 + hi) * L_
                                       + t * 64 + (f & 1) * 32 + l31) * 8);
    };
    auto ldV = [&](int f, int t) -> bf16x8 {   // f: ksj=f>>1, hdf=f&1
        return *(const bf16x8*)(Vpb + ((size_t)(t * 8 + (f >> 1) * 2 + hi) * 64
                                       + (f & 1) * 32 + l31) * 8);
    };

    bf16x8 kr[8], vr[2][4];
#pragma unroll
    for (int i = 0; i < 4; i++) vr[0][i] = ldV(w * 4 + i, 0);
#pragma unroll
    for (int i = 0; i < 4; i++) *(bf16x8*)(&Vb[0][w * 4 + i][lane][0]) = vr[0][i];
#pragma unroll
    for (int i = 0; i < 4; i++) vr[1][i] = ldV(w * 4 + i, 1);
#pragma unroll
    for (int i = 0; i < 4; i++) vr[0][i] = ldV(w * 4 + i, 2);
#pragma unroll
    for (int f = 0; f < 8; f++) kr[f] = ldK(f, 0);
    __syncthreads();

    auto tile_body = [&](int t, int cur, int nxt) {
        // S^T = K @ Q^T, C-layout; K operands straight from global regs.
        f32x16 s0 = mfma32(kr[0], qf[0], zz);
        f32x16 s1 = mfma32(kr[1], qf[0], zz);
#pragma unroll
        for (int ks = 1; ks < 4; ks++) {
            s0 = mfma32(kr[ks * 2 + 0], qf[ks], s0);
            s1 = mfma32(kr[ks * 2 + 1], qf[ks], s1);
        }
        if (t < 31) {
#pragma unroll
            for (int f = 0; f < 8; f++) kr[f] = ldK(f, t + 1);
        }

        // half 0: exp2 -> P frags (natural order, PI-matched) -> PV + row-sum
#pragma unroll
        for (int r = 0; r < 16; r++) s0[r] = __builtin_amdgcn_exp2f(s0[r]);
        {
            bf16x8 pf0, pf1;
#pragma unroll
            for (int u = 0; u < 8; u++) { pf0[u] = (bf16)s0[u]; pf1[u] = (bf16)s0[8 + u]; }
            o0   = mfma32(pf0, *(const bf16x8*)(&Vb[cur][0][lane][0]), o0);
            o1   = mfma32(pf0, *(const bf16x8*)(&Vb[cur][1][lane][0]), o1);
            lacc = mfma32(pf0, ones, lacc);
            o0   = mfma32(pf1, *(const bf16x8*)(&Vb[cur][2][lane][0]), o0);
            o1   = mfma32(pf1, *(const bf16x8*)(&Vb[cur][3][lane][0]), o1);
            lacc = mfma32(pf1, ones, lacc);
        }
        // half 1
#pragma unroll
        for (int r = 0; r < 16; r++) s1[r] = __builtin_amdgcn_exp2f(s1[r]);
        {
            bf16x8 pf2, pf3;
#pragma unroll
            for (int u = 0; u < 8; u++) { pf2[u] = (bf16)s1[u]; pf3[u] = (bf16)s1[8 + u]; }
            o0   = mfma32(pf2, *(const bf16x8*)(&Vb[cur][4][lane][0]), o0);
            o1   = mfma32(pf2, *(const bf16x8*)(&Vb[cur][5][lane][0]), o1);
            lacc = mfma32(pf2, ones, lacc);
            o0   = mfma32(pf3, *(const bf16x8*)(&Vb[cur][6][lane][0]), o0);
            o1   = mfma32(pf3, *(const bf16x8*)(&Vb[cur][7][lane][0]), o1);
            lacc = mfma32(pf3, ones, lacc);
        }

        if (t < 31) {
            // store tile t+1 (loaded 2 tiles ago), then refill with tile t+3
#pragma unroll
            for (int i = 0; i < 4; i++)
                *(bf16x8*)(&Vb[1 - cur][w * 4 + i][lane][0]) = vr[nxt][i];
            const int tn = (t + 3 < 32) ? t + 3 : 31;
#pragma unroll
            for (int i = 0; i < 4; i++) vr[nxt][i] = ldV(w * 4 + i, tn);
            __syncthreads();
        }
    };

    for (int tt = 0; tt < 16; tt++) {
        tile_body(2 * tt + 0, 0, 1);
        tile_body(2 * tt + 1, 1, 0);
    }

    // Epilogue: lacc rows carry this lane's q-row sums (all n-cols identical).
    const int b = bh >> 3, h = bh & 7;
#pragma unroll
    for (int r = 0; r < 16; r++) {
        const int rl = (r & 3) + 8 * (r >> 2) + 4 * hi;
        const float inv = 1.0f / lacc[r];
        const int m = b * L_ + qb + rl;
        const int c0 = h * HD_ + l31;
        Op[((size_t)(c0 >> 3) * M_ + m) * 8 + (c0 & 7)] = (bf16)(o0[r] * inv);
        const int c1 = c0 + 32;
        Op[((size_t)(c1 >> 3) * M_ + m) * 8 + (c1 & 7)] = (bf16)(o1[r] * inv);
    }
}

extern "C" void kernel_launch(void* const* d_in, const int* in_sizes, int n_in,
                              void* d_out, int out_size, void* d_ws, size_t ws_size,
                              hipStream_t stream)
{
    (void)in_sizes; (void)n_in; (void)out_size;
    const float* q  = (const float*)d_in[0];
    const float* k  = (const float*)d_in[1];
    const float* v  = (const float*)d_in[2];
    const float* Wq = (const float*)d_in[3];
    const float* bq = (const float*)d_in[4];
    const float* Wk = (const float*)d_in[5];
    const float* bk = (const float*)d_in[6];
    const float* Wv = (const float*)d_in[7];
    const float* bv = (const float*)d_in[8];
    const float* Wo = (const float*)d_in[9];
    const float* bo = (const float*)d_in[10];
    float* out = (float*)d_out;

    // ws: P0 @0, P1 @8M, P2 @16M, Wp @24M (2 MB), [VpN @26M if room].
    // d_out (16 MB): qh @0, Kp @8M -- both dead before the final projection.
    // Fallback (ws < 34MB): Vp overwrites P0 (needs serialized proj_v).
    // Op overwrites P1 (Xk dead after the q/k/v projections).
    char* ws = (char*)d_ws;
    const size_t MB = 1024 * 1024;
    bf16* P0  = (bf16*)(ws);
    bf16* P1  = (bf16*)(ws + 8 * MB);
    bf16* P2  = (bf16*)(ws + 16 * MB);
    bf16* Wp  = (bf16*)(ws + 24 * MB);
    bf16* qh  = (bf16*)(d_out);
    bf16* Kp  = (bf16*)((char*)d_out + 8 * MB);
    bf16* Opb = P1;

    bf16* Wqp = Wp;
    bf16* Wkp = Wp + (size_t)64 * 512 * 8;
    bf16* Wvp = Wp + (size_t)2 * 64 * 512 * 8;
    bf16* Wop = Wp + (size_t)3 * 64 * 512 * 8;

    const float SCALE_LOG2E = 0.06377946282349575f;  // (1/sqrt(512))*log2(e)

    dim3 pb(256);
    pack_all<<<dim3(128, 8, 7), pb, 0, stream>>>(q, k, v, Wq, Wk, Wv, Wo,
                                                 Wp, P0, P1, P2);

    if (ws_size >= (size_t)34 * MB) {
        // Merged path: all three projections in one launch (independent
        // outputs; Vp gets fresh workspace so it doesn't alias Xq=P0).
        bf16* VpN = (bf16*)(ws + 26 * MB);
        PJob jq{P0, Wqp, bq, qh,  SCALE_LOG2E, 0};
        PJob jk{P1, Wkp, bk, Kp,  1.0f, 1};
        PJob jv{P2, Wvp, bv, VpN, 1.0f, 3};
        proj_kernel<<<dim3(64, 4, 3), pb, 0, stream>>>(jq, jk, jv);

        attn_kernel<<<dim3(32, 32), dim3(128), 0, stream>>>(qh, Kp, VpN, Opb);
    } else {
        bf16* Vp = P0;
        PJob jq{P0, Wqp, bq, qh, SCALE_LOG2E, 0};
        PJob jk{P1, Wkp, bk, Kp, 1.0f, 1};
        proj_kernel<<<dim3(64, 4, 2), pb, 0, stream>>>(jq, jk, jk);

        PJob jv{P2, Wvp, bv, Vp, 1.0f, 3};
        proj_kernel<<<dim3(64, 4, 1), pb, 0, stream>>>(jv, jv, jv);

        attn_kernel<<<dim3(32, 32), dim3(128), 0, stream>>>(qh, Kp, Vp, Opb);
    }

    PJob jo{Opb, Wop, bo, out, 1.0f, 2};
    proj_kernel<<<dim3(64, 4, 1), pb, 0, stream>>>(jo, jo, jo);
}

// Round 8
// 196.980 us; speedup vs baseline: 2.3469x; 1.0237x over previous
//
#include <hip/hip_runtime.h>
#include <hip/hip_bf16.h>

#define B_  4
#define L_  2048
#define D_  512
#define H_  8
#define HD_ 64
#define M_  (B_ * L_)   // 8192

typedef __bf16 bf16;
typedef __attribute__((ext_vector_type(8)))  __bf16 bf16x8;
typedef __attribute__((ext_vector_type(4)))  __bf16 bf16x4;
typedef __attribute__((ext_vector_type(16))) float  f32x16;

__device__ __forceinline__ f32x16 mfma32(bf16x8 a, bf16x8 b, f32x16 c) {
    return __builtin_amdgcn_mfma_f32_32x32x16_bf16(a, b, c, 0, 0, 0);
}

// ---- pack: src fp32 [R][512] -> dst bf16 panels [64][R][8] ----
__device__ __forceinline__ void pack_body(const float* __restrict__ src,
                                          bf16* __restrict__ dst, int R,
                                          int m0, int k0)
{
    __shared__ __align__(16) bf16 tile[64][76];
    const int t = threadIdx.x;
#pragma unroll
    for (int rep = 0; rep < 4; rep++) {
        const int idx = rep * 256 + t;
        const int r = idx >> 4, c4 = idx & 15;
        const float4 f = *(const float4*)(src + (size_t)(m0 + r) * 512 + k0 + c4 * 4);
        bf16x4 v; v[0] = (bf16)f.x; v[1] = (bf16)f.y; v[2] = (bf16)f.z; v[3] = (bf16)f.w;
        *(bf16x4*)(&tile[r][c4 * 4]) = v;
    }
    __syncthreads();
#pragma unroll
    for (int rep = 0; rep < 2; rep++) {
        const int s = rep * 256 + t;
        const int ml = s & 63, kpl = s >> 6;
        const bf16x4 lo = *(const bf16x4*)(&tile[ml][kpl * 8]);
        const bf16x4 hi4 = *(const bf16x4*)(&tile[ml][kpl * 8 + 4]);
        bf16x8 v;
#pragma unroll
        for (int e = 0; e < 4; e++) { v[e] = lo[e]; v[e + 4] = hi4[e]; }
        *(bf16x8*)(dst + ((size_t)(k0 / 8 + kpl) * R + m0 + ml) * 8) = v;
    }
}

// z<4: weight z (blockIdx.x<8); z=4: q->P0; z=5: k->P1; z=6: v->P2.
// grid (128, 8, 7), block 256.
__global__ __launch_bounds__(256) void pack_all(
    const float* __restrict__ q, const float* __restrict__ k,
    const float* __restrict__ v,
    const float* __restrict__ W0, const float* __restrict__ W1,
    const float* __restrict__ W2, const float* __restrict__ W3,
    bf16* __restrict__ Wp, bf16* __restrict__ P0, bf16* __restrict__ P1,
    bf16* __restrict__ P2)
{
    const int z = blockIdx.z;
    if (z < 4) {
        if (blockIdx.x >= 8) return;
        const float* src = z == 0 ? W0 : z == 1 ? W1 : z == 2 ? W2 : W3;
        pack_body(src, Wp + (size_t)z * 64 * 512 * 8, 512, blockIdx.x * 64, blockIdx.y * 64);
    } else {
        const float* src = z == 4 ? q : z == 5 ? k : v;
        bf16* dst = z == 4 ? P0 : z == 5 ? P1 : P2;
        pack_body(src, dst, M_, blockIdx.x * 64, blockIdx.y * 64);
    }
}

// ---- projection: relu(Xp @ Wp^T + b) (*postmul) ----
// ROUND-8.  R7 cross-round arithmetic proved the 128x128/k64 rebuild was
// ~14 us SLOWER than the old 128x64 proj: 64 KB LDS capped 2 blocks/CU and
// grid 768 left a 50% residency tail (and o-proj sat at 1 block/CU).
// Fix: SAME 128x128 tile and 4-chain ILP, but k-step 32 -> LDS 32 KB
// (2 x (8+8) KB) and ~140 VGPR -> 3 blocks/CU.  Grid (64,4): z3 = 768
// blocks = EXACTLY 3/CU, 100% residency, 12 waves/CU = 3 waves/SIMD --
// the old proj's TLP with double the per-barrier MFMA ILP.  16 k-steps,
// 2-deep register prefetch, per step: 8 ds_read_b128 + 8 MFMA/wave.
// Output modes: 0 bf16 [B,H,L,HD]; 1 K-panels [BH][8][L][8]; 2 fp32
// [M,512]; 3 V-panels [BH][256][64][8] PI-swizzled.
struct PJob {
    const bf16* X; const bf16* W; const float* bias; void* out;
    float postmul; int mode;
};

__global__ __launch_bounds__(256, 3) void proj_kernel(PJob j0, PJob j1, PJob j2)
{
    const PJob jb = (blockIdx.z == 0) ? j0 : (blockIdx.z == 1) ? j1 : j2;
    const int w    = threadIdx.x >> 6;
    const int lane = threadIdx.x & 63;
    const int l31  = lane & 31;
    const int hi   = lane >> 5;
    const int m0 = blockIdx.x * 128;
    const int n0 = blockIdx.y * 128;
    const int mh = w & 1;
    const int nh = w >> 1;

    __shared__ __align__(16) bf16 Ab[2][8][64][8];   // 2 x 8 KB
    __shared__ __align__(16) bf16 Bb[2][8][64][8];   // 2 x 8 KB

    f32x16 acc[2][2];
#pragma unroll
    for (int mi = 0; mi < 2; mi++)
#pragma unroll
        for (int ni = 0; ni < 2; ni++)
#pragma unroll
            for (int r = 0; r < 16; r++) acc[mi][ni][r] = 0.0f;

    // slot f (0..7): ks = f>>2 (16-wide k slice), sub = f&3 (32-wide m/n).
    auto ldA = [&](int f, int k0) -> bf16x8 {
        return *(const bf16x8*)(jb.X + ((size_t)((k0 >> 3) + (f >> 2) * 2 + hi) * M_
                                        + m0 + (f & 3) * 32 + l31) * 8);
    };
    auto ldB = [&](int f, int k0) -> bf16x8 {
        return *(const bf16x8*)(jb.W + ((size_t)((k0 >> 3) + (f >> 2) * 2 + hi) * 512
                                        + n0 + (f & 3) * 32 + l31) * 8);
    };

    // wave w stages slots {2w, 2w+1}; 2-deep register prefetch sets.
    bf16x8 rA[2][2], rB[2][2];
#pragma unroll
    for (int i = 0; i < 2; i++) { rA[0][i] = ldA(w * 2 + i, 0);  rB[0][i] = ldB(w * 2 + i, 0); }
#pragma unroll
    for (int i = 0; i < 2; i++) {
        *(bf16x8*)(&Ab[0][w * 2 + i][lane][0]) = rA[0][i];
        *(bf16x8*)(&Bb[0][w * 2 + i][lane][0]) = rB[0][i];
    }
#pragma unroll
    for (int i = 0; i < 2; i++) { rA[1][i] = ldA(w * 2 + i, 32); rB[1][i] = ldB(w * 2 + i, 32); }
#pragma unroll
    for (int i = 0; i < 2; i++) { rA[0][i] = ldA(w * 2 + i, 64); rB[0][i] = ldB(w * 2 + i, 64); }
    __syncthreads();

#pragma unroll
    for (int it = 0; it < 16; it++) {
        const int cur = it & 1;
#pragma unroll
        for (int ks = 0; ks < 2; ks++) {
            const bf16x8 a0 = *(const bf16x8*)(&Ab[cur][ks * 4 + mh * 2 + 0][lane][0]);
            const bf16x8 a1 = *(const bf16x8*)(&Ab[cur][ks * 4 + mh * 2 + 1][lane][0]);
            const bf16x8 b0 = *(const bf16x8*)(&Bb[cur][ks * 4 + nh * 2 + 0][lane][0]);
            const bf16x8 b1 = *(const bf16x8*)(&Bb[cur][ks * 4 + nh * 2 + 1][lane][0]);
            acc[0][0] = mfma32(a0, b0, acc[0][0]);
            acc[0][1] = mfma32(a0, b1, acc[0][1]);
            acc[1][0] = mfma32(a1, b0, acc[1][0]);
            acc[1][1] = mfma32(a1, b1, acc[1][1]);
        }
        if (it < 15) {
            const int s = (it + 1) & 1;          // set holding k_{it+1}
#pragma unroll
            for (int i = 0; i < 2; i++) {
                *(bf16x8*)(&Ab[1 - cur][w * 2 + i][lane][0]) = rA[s][i];
                *(bf16x8*)(&Bb[1 - cur][w * 2 + i][lane][0]) = rB[s][i];
            }
            if (it < 13) {                       // refill set with k_{it+3}
#pragma unroll
                for (int i = 0; i < 2; i++) {
                    rA[s][i] = ldA(w * 2 + i, (it + 3) * 32);
                    rB[s][i] = ldB(w * 2 + i, (it + 3) * 32);
                }
            }
            __syncthreads();
        }
    }

    const int mode = jb.mode;
#pragma unroll
    for (int ni = 0; ni < 2; ni++) {
        const int col = n0 + (nh * 2 + ni) * 32 + l31;
        const float bn = jb.bias[col];
#pragma unroll
        for (int mi = 0; mi < 2; mi++)
#pragma unroll
            for (int r = 0; r < 16; r++) {
                const int row = m0 + (mh * 2 + mi) * 32 + (r & 3) + 8 * (r >> 2) + 4 * hi;
                float v = fmaxf(acc[mi][ni][r] + bn, 0.0f);
                if (mode == 2) {
                    ((float*)jb.out)[(size_t)row * D_ + col] = v;
                } else {
                    v *= jb.postmul;
                    const int b = row >> 11, l = row & (L_ - 1);
                    const int h = col >> 6,  hd = col & (HD_ - 1);
                    const int bh = b * H_ + h;
                    size_t idx;
                    if (mode == 0) {
                        idx = ((size_t)bh * L_ + l) * HD_ + hd;
                    } else if (mode == 1) {       // K panels [bh][hd>>3][l][hd&7]
                        idx = (((size_t)bh * 8 + (hd >> 3)) * L_ + l) * 8 + (hd & 7);
                    } else {                      // mode 3: V panels, PI-swizzled j
                        const int swzl = (l & ~15) | (l & 3) | ((l & 4) << 1) | ((l & 8) >> 1);
                        idx = (((size_t)bh * 256 + (swzl >> 3)) * 64 + hd) * 8 + (swzl & 7);
                    }
                    ((bf16*)jb.out)[idx] = (bf16)v;
                }
            }
    }
}

// ---- flash attention, max-free (post-ReLU q,k => scores >= 0) ----
// EXACT round-0 structure + XCD-chunked swizzle (R7: 48.4 us, 100 VGPR,
// FETCH 12.3 MB).  DO NOT TOUCH: rounds 2-5 proved every TLP/ILP
// restructuring of this kernel crosses a register-class boundary and
// spills catastrophically.
__global__ __launch_bounds__(128, 2) void attn_kernel(
    const bf16* __restrict__ qh, const bf16* __restrict__ Kp,
    const bf16* __restrict__ Vp, bf16* __restrict__ Op)
{
    const int w    = threadIdx.x >> 6;   // 0..1
    const int lane = threadIdx.x & 63;
    const int l31  = lane & 31;
    const int hi   = lane >> 5;

    const int lin  = blockIdx.x + (blockIdx.y << 5);   // grid (32,32)
    const int xcd  = lin & 7;
    const int slot = lin >> 3;                          // 0..127 within XCD
    const int bh   = (xcd << 2) + (slot >> 5);          // 4 bh per XCD
    const int qb   = (slot & 31) * 64 + w * 32;

    const bf16* Q   = qh + (size_t)bh * L_ * HD_;
    const bf16* Kpb = Kp + (size_t)bh * 8 * L_ * 8;
    const bf16* Vpb = Vp + (size_t)bh * 256 * 64 * 8;

    __shared__ __align__(16) bf16 Vb[2][8][64][8];   // 16 KB

    bf16x8 qf[4];
#pragma unroll
    for (int ks = 0; ks < 4; ks++)
        qf[ks] = *(const bf16x8*)(Q + (size_t)(qb + l31) * HD_ + ks * 16 + hi * 8);

    f32x16 zz;
#pragma unroll
    for (int r = 0; r < 16; r++) zz[r] = 0.0f;
    f32x16 o0 = zz, o1 = zz, lacc = zz;
    bf16x8 ones;
#pragma unroll
    for (int u = 0; u < 8; u++) ones[u] = (bf16)1.0f;

    auto ldK = [&](int f, int t) -> bf16x8 {   // f: ks=f>>1, jt=f&1
        return *(const bf16x8*)(Kpb + ((size_t)((f >> 1) * 2 + hi) * L_
                                       + t * 64 + (f & 1) * 32 + l31) * 8);
    };
    auto ldV = [&](int f, int t) -> bf16x8 {   // f: ksj=f>>1, hdf=f&1
        return *(const bf16x8*)(Vpb + ((size_t)(t * 8 + (f >> 1) * 2 + hi) * 64
                                       + (f & 1) * 32 + l31) * 8);
    };

    bf16x8 kr[8], vr[2][4];
#pragma unroll
    for (int i = 0; i < 4; i++) vr[0][i] = ldV(w * 4 + i, 0);
#pragma unroll
    for (int i = 0; i < 4; i++) *(bf16x8*)(&Vb[0][w * 4 + i][lane][0]) = vr[0][i];
#pragma unroll
    for (int i = 0; i < 4; i++) vr[1][i] = ldV(w * 4 + i, 1);
#pragma unroll
    for (int i = 0; i < 4; i++) vr[0][i] = ldV(w * 4 + i, 2);
#pragma unroll
    for (int f = 0; f < 8; f++) kr[f] = ldK(f, 0);
    __syncthreads();

    auto tile_body = [&](int t, int cur, int nxt) {
        // S^T = K @ Q^T, C-layout; K operands straight from global regs.
        f32x16 s0 = mfma32(kr[0], qf[0], zz);
        f32x16 s1 = mfma32(kr[1], qf[0], zz);
#pragma unroll
        for (int ks = 1; ks < 4; ks++) {
            s0 = mfma32(kr[ks * 2 + 0], qf[ks], s0);
            s1 = mfma32(kr[ks * 2 + 1], qf[ks], s1);
        }
        if (t < 31) {
#pragma unroll
            for (int f = 0; f < 8; f++) kr[f] = ldK(f, t + 1);
        }

        // half 0: exp2 -> P frags (natural order, PI-matched) -> PV + row-sum
#pragma unroll
        for (int r = 0; r < 16; r++) s0[r] = __builtin_amdgcn_exp2f(s0[r]);
        {
            bf16x8 pf0, pf1;
#pragma unroll
            for (int u = 0; u < 8; u++) { pf0[u] = (bf16)s0[u]; pf1[u] = (bf16)s0[8 + u]; }
            o0   = mfma32(pf0, *(const bf16x8*)(&Vb[cur][0][lane][0]), o0);
            o1   = mfma32(pf0, *(const bf16x8*)(&Vb[cur][1][lane][0]), o1);
            lacc = mfma32(pf0, ones, lacc);
            o0   = mfma32(pf1, *(const bf16x8*)(&Vb[cur][2][lane][0]), o0);
            o1   = mfma32(pf1, *(const bf16x8*)(&Vb[cur][3][lane][0]), o1);
            lacc = mfma32(pf1, ones, lacc);
        }
        // half 1
#pragma unroll
        for (int r = 0; r < 16; r++) s1[r] = __builtin_amdgcn_exp2f(s1[r]);
        {
            bf16x8 pf2, pf3;
#pragma unroll
            for (int u = 0; u < 8; u++) { pf2[u] = (bf16)s1[u]; pf3[u] = (bf16)s1[8 + u]; }
            o0   = mfma32(pf2, *(const bf16x8*)(&Vb[cur][4][lane][0]), o0);
            o1   = mfma32(pf2, *(const bf16x8*)(&Vb[cur][5][lane][0]), o1);
            lacc = mfma32(pf2, ones, lacc);
            o0   = mfma32(pf3, *(const bf16x8*)(&Vb[cur][6][lane][0]), o0);
            o1   = mfma32(pf3, *(const bf16x8*)(&Vb[cur][7][lane][0]), o1);
            lacc = mfma32(pf3, ones, lacc);
        }

        if (t < 31) {
            // store tile t+1 (loaded 2 tiles ago), then refill with tile t+3
#pragma unroll
            for (int i = 0; i < 4; i++)
                *(bf16x8*)(&Vb[1 - cur][w * 4 + i][lane][0]) = vr[nxt][i];
            const int tn = (t + 3 < 32) ? t + 3 : 31;
#pragma unroll
            for (int i = 0; i < 4; i++) vr[nxt][i] = ldV(w * 4 + i, tn);
            __syncthreads();
        }
    };

    for (int tt = 0; tt < 16; tt++) {
        tile_body(2 * tt + 0, 0, 1);
        tile_body(2 * tt + 1, 1, 0);
    }

    // Epilogue: lacc rows carry this lane's q-row sums (all n-cols identical).
    const int b = bh >> 3, h = bh & 7;
#pragma unroll
    for (int r = 0; r < 16; r++) {
        const int rl = (r & 3) + 8 * (r >> 2) + 4 * hi;
        const float inv = 1.0f / lacc[r];
        const int m = b * L_ + qb + rl;
        const int c0 = h * HD_ + l31;
        Op[((size_t)(c0 >> 3) * M_ + m) * 8 + (c0 & 7)] = (bf16)(o0[r] * inv);
        const int c1 = c0 + 32;
        Op[((size_t)(c1 >> 3) * M_ + m) * 8 + (c1 & 7)] = (bf16)(o1[r] * inv);
    }
}

extern "C" void kernel_launch(void* const* d_in, const int* in_sizes, int n_in,
                              void* d_out, int out_size, void* d_ws, size_t ws_size,
                              hipStream_t stream)
{
    (void)in_sizes; (void)n_in; (void)out_size;
    const float* q  = (const float*)d_in[0];
    const float* k  = (const float*)d_in[1];
    const float* v  = (const float*)d_in[2];
    const float* Wq = (const float*)d_in[3];
    const float* bq = (const float*)d_in[4];
    const float* Wk = (const float*)d_in[5];
    const float* bk = (const float*)d_in[6];
    const float* Wv = (const float*)d_in[7];
    const float* bv = (const float*)d_in[8];
    const float* Wo = (const float*)d_in[9];
    const float* bo = (const float*)d_in[10];
    float* out = (float*)d_out;

    // ws: P0 @0, P1 @8M, P2 @16M, Wp @24M (2 MB), [VpN @26M if room].
    // d_out (16 MB): qh @0, Kp @8M -- both dead before the final projection.
    // Fallback (ws < 34MB): Vp overwrites P0 (needs serialized proj_v).
    // Op overwrites P1 (Xk dead after the q/k/v projections).
    char* ws = (char*)d_ws;
    const size_t MB = 1024 * 1024;
    bf16* P0  = (bf16*)(ws);
    bf16* P1  = (bf16*)(ws + 8 * MB);
    bf16* P2  = (bf16*)(ws + 16 * MB);
    bf16* Wp  = (bf16*)(ws + 24 * MB);
    bf16* qh  = (bf16*)(d_out);
    bf16* Kp  = (bf16*)((char*)d_out + 8 * MB);
    bf16* Opb = P1;

    bf16* Wqp = Wp;
    bf16* Wkp = Wp + (size_t)64 * 512 * 8;
    bf16* Wvp = Wp + (size_t)2 * 64 * 512 * 8;
    bf16* Wop = Wp + (size_t)3 * 64 * 512 * 8;

    const float SCALE_LOG2E = 0.06377946282349575f;  // (1/sqrt(512))*log2(e)

    dim3 pb(256);
    pack_all<<<dim3(128, 8, 7), pb, 0, stream>>>(q, k, v, Wq, Wk, Wv, Wo,
                                                 Wp, P0, P1, P2);

    if (ws_size >= (size_t)34 * MB) {
        // Merged path: all three projections in one launch (independent
        // outputs; Vp gets fresh workspace so it doesn't alias Xq=P0).
        bf16* VpN = (bf16*)(ws + 26 * MB);
        PJob jq{P0, Wqp, bq, qh,  SCALE_LOG2E, 0};
        PJob jk{P1, Wkp, bk, Kp,  1.0f, 1};
        PJob jv{P2, Wvp, bv, VpN, 1.0f, 3};
        proj_kernel<<<dim3(64, 4, 3), pb, 0, stream>>>(jq, jk, jv);

        attn_kernel<<<dim3(32, 32), dim3(128), 0, stream>>>(qh, Kp, VpN, Opb);
    } else {
        bf16* Vp = P0;
        PJob jq{P0, Wqp, bq, qh, SCALE_LOG2E, 0};
        PJob jk{P1, Wkp, bk, Kp, 1.0f, 1};
        proj_kernel<<<dim3(64, 4, 2), pb, 0, stream>>>(jq, jk, jk);

        PJob jv{P2, Wvp, bv, Vp, 1.0f, 3};
        proj_kernel<<<dim3(64, 4, 1), pb, 0, stream>>>(jv, jv, jv);

        attn_kernel<<<dim3(32, 32), dim3(128), 0, stream>>>(qh, Kp, Vp, Opb);
    }

    PJob jo{Opb, Wop, bo, out, 1.0f, 2};
    proj_kernel<<<dim3(64, 4, 1), pb, 0, stream>>>(jo, jo, jo);
}

// Round 10
// 192.709 us; speedup vs baseline: 2.3989x; 1.0222x over previous
//
#include <hip/hip_runtime.h>
#include <hip/hip_bf16.h>

#define B_  4
#define L_  2048
#define D_  512
#define H_  8
#define HD_ 64
#define M_  (B_ * L_)   // 8192

typedef __bf16 bf16;
typedef __attribute__((ext_vector_type(8)))  __bf16 bf16x8;
typedef __attribute__((ext_vector_type(4)))  __bf16 bf16x4;
typedef __attribute__((ext_vector_type(16))) float  f32x16;

__device__ __forceinline__ f32x16 mfma32(bf16x8 a, bf16x8 b, f32x16 c) {
    return __builtin_amdgcn_mfma_f32_32x32x16_bf16(a, b, c, 0, 0, 0);
}

// ---- pack: src fp32 [R][512] -> dst bf16 panels [64][R][8] ----
__device__ __forceinline__ void pack_body(const float* __restrict__ src,
                                          bf16* __restrict__ dst, int R,
                                          int m0, int k0)
{
    __shared__ __align__(16) bf16 tile[64][76];
    const int t = threadIdx.x;
#pragma unroll
    for (int rep = 0; rep < 4; rep++) {
        const int idx = rep * 256 + t;
        const int r = idx >> 4, c4 = idx & 15;
        const float4 f = *(const float4*)(src + (size_t)(m0 + r) * 512 + k0 + c4 * 4);
        bf16x4 v; v[0] = (bf16)f.x; v[1] = (bf16)f.y; v[2] = (bf16)f.z; v[3] = (bf16)f.w;
        *(bf16x4*)(&tile[r][c4 * 4]) = v;
    }
    __syncthreads();
#pragma unroll
    for (int rep = 0; rep < 2; rep++) {
        const int s = rep * 256 + t;
        const int ml = s & 63, kpl = s >> 6;
        const bf16x4 lo = *(const bf16x4*)(&tile[ml][kpl * 8]);
        const bf16x4 hi4 = *(const bf16x4*)(&tile[ml][kpl * 8 + 4]);
        bf16x8 v;
#pragma unroll
        for (int e = 0; e < 4; e++) { v[e] = lo[e]; v[e + 4] = hi4[e]; }
        *(bf16x8*)(dst + ((size_t)(k0 / 8 + kpl) * R + m0 + ml) * 8) = v;
    }
}

// Weights ONLY -- q/k/v transpose is fused into proj_qkv (round 9).
// grid (8, 8, 4), block 256.
__global__ __launch_bounds__(256) void pack_w(
    const float* __restrict__ W0, const float* __restrict__ W1,
    const float* __restrict__ W2, const float* __restrict__ W3,
    bf16* __restrict__ Wp)
{
    const int z = blockIdx.z;
    const float* src = z == 0 ? W0 : z == 1 ? W1 : z == 2 ? W2 : W3;
    pack_body(src, Wp + (size_t)z * 64 * 512 * 8, 512, blockIdx.x * 64, blockIdx.y * 64);
}

// ---- projection: relu(X @ W^T + b) (*postmul) ----
// R8 structure (tile 128x128, k-step 32, 3 blocks/CU, 1 barrier/step,
// 2-deep register prefetch) with a templated A path:
//   FP32A=false: X = bf16 panels [K/8][M][8] (o-projection).
//   FP32A=true : X = RAW fp32 [M][512].  R6's fused attempt failed because
//     it skipped the transpose (2KB-strided lanes).  Correct fusion: thread
//     loads float4 X[m0+r][k0+c4*4] (coalesced, 8 thr/row = 128B groups);
//     its 4 consecutive k stay inside ONE bf16x4 of the panel slot:
//       Ab[((c4>>2)<<2)|(r>>5)][(r&31)|(((c4>>1)&1)<<5)][(c4&1)*4]
//     (identity: k = k0+(c4>>2)*16+((c4>>1)&1)*8+(c4&1)*4+e = k0+c4*4+e).
//     Direct 8B LDS writes, no intermediate tile, no extra barrier.  This
//     deletes the pack_all staging pass for q/k/v (-48MB HBM round trip)
//     and frees P0/P1/P2 so the merged z3 launch always fits in 18MB ws.
// Output modes: 0 bf16 [B,H,L,HD]; 1 K-panels [BH][8][L][8]; 2 fp32
// [M,512]; 3 V-panels [BH][256][64][8] PI-swizzled.
struct PJob {
    const bf16* X; const float* Xf; const bf16* W; const float* bias;
    void* out; float postmul; int mode;
};

template<bool FP32A>
__device__ __forceinline__ void proj_body(const PJob jb)
{
    const int w    = threadIdx.x >> 6;
    const int lane = threadIdx.x & 63;
    const int l31  = lane & 31;
    const int hi   = lane >> 5;
    const int m0 = blockIdx.x * 128;
    const int n0 = blockIdx.y * 128;
    const int mh = w & 1;
    const int nh = w >> 1;

    __shared__ __align__(16) bf16 Ab[2][8][64][8];   // 2 x 8 KB
    __shared__ __align__(16) bf16 Bb[2][8][64][8];   // 2 x 8 KB

    f32x16 acc[2][2];
#pragma unroll
    for (int mi = 0; mi < 2; mi++)
#pragma unroll
        for (int ni = 0; ni < 2; ni++)
#pragma unroll
            for (int r = 0; r < 16; r++) acc[mi][ni][r] = 0.0f;

    // slot f (0..7): ks = f>>2 (16-wide k slice), sub = f&3 (32-wide m/n).
    auto ldA = [&](int f, int k0) -> bf16x8 {   // panel path
        return *(const bf16x8*)(jb.X + ((size_t)((k0 >> 3) + (f >> 2) * 2 + hi) * M_
                                        + m0 + (f & 3) * 32 + l31) * 8);
    };
    auto ldB = [&](int f, int k0) -> bf16x8 {
        return *(const bf16x8*)(jb.W + ((size_t)((k0 >> 3) + (f >> 2) * 2 + hi) * 512
                                        + n0 + (f & 3) * 32 + l31) * 8);
    };

    bf16x8 rA[2][2], rB[2][2];
    float4 rT[2][4];

    auto ldT = [&](int s, int k0) {             // fp32 path: 4 float4/thread
#pragma unroll
        for (int rep = 0; rep < 4; rep++) {
            const int idx = rep * 256 + (int)threadIdx.x;
            rT[s][rep] = *(const float4*)(jb.Xf + (size_t)(m0 + (idx >> 3)) * 512
                                          + k0 + (idx & 7) * 4);
        }
    };
    auto stA = [&](int s, int buf) {            // convert + direct panel write
#pragma unroll
        for (int rep = 0; rep < 4; rep++) {
            const int idx = rep * 256 + (int)threadIdx.x;
            const int r = idx >> 3, c4 = idx & 7;
            const float4 f = rT[s][rep];
            bf16x4 v; v[0] = (bf16)f.x; v[1] = (bf16)f.y;
            v[2] = (bf16)f.z; v[3] = (bf16)f.w;
            const int fs = ((c4 >> 2) << 2) | (r >> 5);
            const int ln = (r & 31) | (((c4 >> 1) & 1) << 5);
            *(bf16x4*)(&Ab[buf][fs][ln][(c4 & 1) * 4]) = v;
        }
    };

    // prologue: k0 -> LDS0; k32 -> set1; k64 -> set0.
    if constexpr (FP32A) {
        ldT(0, 0); stA(0, 0); ldT(1, 32); ldT(0, 64);
    } else {
#pragma unroll
        for (int i = 0; i < 2; i++) rA[0][i] = ldA(w * 2 + i, 0);
#pragma unroll
        for (int i = 0; i < 2; i++)
            *(bf16x8*)(&Ab[0][w * 2 + i][lane][0]) = rA[0][i];
#pragma unroll
        for (int i = 0; i < 2; i++) rA[1][i] = ldA(w * 2 + i, 32);
#pragma unroll
        for (int i = 0; i < 2; i++) rA[0][i] = ldA(w * 2 + i, 64);
    }
#pragma unroll
    for (int i = 0; i < 2; i++) rB[0][i] = ldB(w * 2 + i, 0);
#pragma unroll
    for (int i = 0; i < 2; i++)
        *(bf16x8*)(&Bb[0][w * 2 + i][lane][0]) = rB[0][i];
#pragma unroll
    for (int i = 0; i < 2; i++) rB[1][i] = ldB(w * 2 + i, 32);
#pragma unroll
    for (int i = 0; i < 2; i++) rB[0][i] = ldB(w * 2 + i, 64);
    __syncthreads();

#pragma unroll
    for (int it = 0; it < 16; it++) {
        const int cur = it & 1;
#pragma unroll
        for (int ks = 0; ks < 2; ks++) {
            const bf16x8 a0 = *(const bf16x8*)(&Ab[cur][ks * 4 + mh * 2 + 0][lane][0]);
            const bf16x8 a1 = *(const bf16x8*)(&Ab[cur][ks * 4 + mh * 2 + 1][lane][0]);
            const bf16x8 b0 = *(const bf16x8*)(&Bb[cur][ks * 4 + nh * 2 + 0][lane][0]);
            const bf16x8 b1 = *(const bf16x8*)(&Bb[cur][ks * 4 + nh * 2 + 1][lane][0]);
            acc[0][0] = mfma32(a0, b0, acc[0][0]);
            acc[0][1] = mfma32(a0, b1, acc[0][1]);
            acc[1][0] = mfma32(a1, b0, acc[1][0]);
            acc[1][1] = mfma32(a1, b1, acc[1][1]);
        }
        if (it < 15) {
            const int s = (it + 1) & 1;          // set holding k_{it+1}
            if constexpr (FP32A) {
                stA(s, 1 - cur);
            } else {
#pragma unroll
                for (int i = 0; i < 2; i++)
                    *(bf16x8*)(&Ab[1 - cur][w * 2 + i][lane][0]) = rA[s][i];
            }
#pragma unroll
            for (int i = 0; i < 2; i++)
                *(bf16x8*)(&Bb[1 - cur][w * 2 + i][lane][0]) = rB[s][i];
            if (it < 13) {                       // refill set with k_{it+3}
                if constexpr (FP32A) {
                    ldT(s, (it + 3) * 32);
                } else {
#pragma unroll
                    for (int i = 0; i < 2; i++)
                        rA[s][i] = ldA(w * 2 + i, (it + 3) * 32);
                }
#pragma unroll
                for (int i = 0; i < 2; i++)
                    rB[s][i] = ldB(w * 2 + i, (it + 3) * 32);
            }
            __syncthreads();
        }
    }

    const int mode = jb.mode;
#pragma unroll
    for (int ni = 0; ni < 2; ni++) {
        const int col = n0 + (nh * 2 + ni) * 32 + l31;
        const float bn = jb.bias[col];
#pragma unroll
        for (int mi = 0; mi < 2; mi++)
#pragma unroll
            for (int r = 0; r < 16; r++) {
                const int row = m0 + (mh * 2 + mi) * 32 + (r & 3) + 8 * (r >> 2) + 4 * hi;
                float v = fmaxf(acc[mi][ni][r] + bn, 0.0f);
                if (mode == 2) {
                    ((float*)jb.out)[(size_t)row * D_ + col] = v;
                } else {
                    v *= jb.postmul;
                    const int b = row >> 11, l = row & (L_ - 1);
                    const int h = col >> 6,  hd = col & (HD_ - 1);
                    const int bh = b * H_ + h;
                    size_t idx;
                    if (mode == 0) {
                        idx = ((size_t)bh * L_ + l) * HD_ + hd;
                    } else if (mode == 1) {       // K panels [bh][hd>>3][l][hd&7]
                        idx = (((size_t)bh * 8 + (hd >> 3)) * L_ + l) * 8 + (hd & 7);
                    } else {                      // mode 3: V panels, PI-swizzled j
                        const int swzl = (l & ~15) | (l & 3) | ((l & 4) << 1) | ((l & 8) >> 1);
                        idx = (((size_t)bh * 256 + (swzl >> 3)) * 64 + hd) * 8 + (swzl & 7);
                    }
                    ((bf16*)jb.out)[idx] = (bf16)v;
                }
            }
    }
}

__global__ __launch_bounds__(256, 3) void proj_kernel(PJob j0, PJob j1, PJob j2)
{
    const PJob jb = (blockIdx.z == 0) ? j0 : (blockIdx.z == 1) ? j1 : j2;
    proj_body<false>(jb);
}

__global__ __launch_bounds__(256, 3) void proj_qkv_kernel(PJob j0, PJob j1, PJob j2)
{
    const PJob jb = (blockIdx.z == 0) ? j0 : (blockIdx.z == 1) ? j1 : j2;
    proj_body<true>(jb);
}

// ---- flash attention, max-free (post-ReLU q,k => scores >= 0) ----
// EXACT round-0 structure + XCD-chunked swizzle (R7/R8: 48.4-48.7 us,
// 100 VGPR, FETCH 12.3 MB).  DO NOT TOUCH: rounds 2-5 proved every TLP/ILP
// restructuring crosses a register-class boundary and spills.
__global__ __launch_bounds__(128, 2) void attn_kernel(
    const bf16* __restrict__ qh, const bf16* __restrict__ Kp,
    const bf16* __restrict__ Vp, bf16* __restrict__ Op)
{
    const int w    = threadIdx.x >> 6;   // 0..1
    const int lane = threadIdx.x & 63;
    const int l31  = lane & 31;
    const int hi   = lane >> 5;

    const int lin  = blockIdx.x + (blockIdx.y << 5);   // grid (32,32)
    const int xcd  = lin & 7;
    const int slot = lin >> 3;                          // 0..127 within XCD
    const int bh   = (xcd << 2) + (slot >> 5);          // 4 bh per XCD
    const int qb   = (slot & 31) * 64 + w * 32;

    const bf16* Q   = qh + (size_t)bh * L_ * HD_;
    const bf16* Kpb = Kp + (size_t)bh * 8 * L_ * 8;
    const bf16* Vpb = Vp + (size_t)bh * 256 * 64 * 8;

    __shared__ __align__(16) bf16 Vb[2][8][64][8];   // 16 KB

    bf16x8 qf[4];
#pragma unroll
    for (int ks = 0; ks < 4; ks++)
        qf[ks] = *(const bf16x8*)(Q + (size_t)(qb + l31) * HD_ + ks * 16 + hi * 8);

    f32x16 zz;
#pragma unroll
    for (int r = 0; r < 16; r++) zz[r] = 0.0f;
    f32x16 o0 = zz, o1 = zz, lacc = zz;
    bf16x8 ones;
#pragma unroll
    for (int u = 0; u < 8; u++) ones[u] = (bf16)1.0f;

    auto ldK = [&](int f, int t) -> bf16x8 {   // f: ks=f>>1, jt=f&1
        return *(const bf16x8*)(Kpb + ((size_t)((f >> 1) * 2 + hi) * L_
                                       + t * 64 + (f & 1) * 32 + l31) * 8);
    };
    auto ldV = [&](int f, int t) -> bf16x8 {   // f: ksj=f>>1, hdf=f&1
        return *(const bf16x8*)(Vpb + ((size_t)(t * 8 + (f >> 1) * 2 + hi) * 64
                                       + (f & 1) * 32 + l31) * 8);
    };

    bf16x8 kr[8], vr[2][4];
#pragma unroll
    for (int i = 0; i < 4; i++) vr[0][i] = ldV(w * 4 + i, 0);
#pragma unroll
    for (int i = 0; i < 4; i++) *(bf16x8*)(&Vb[0][w * 4 + i][lane][0]) = vr[0][i];
#pragma unroll
    for (int i = 0; i < 4; i++) vr[1][i] = ldV(w * 4 + i, 1);
#pragma unroll
    for (int i = 0; i < 4; i++) vr[0][i] = ldV(w * 4 + i, 2);
#pragma unroll
    for (int f = 0; f < 8; f++) kr[f] = ldK(f, 0);
    __syncthreads();

    auto tile_body = [&](int t, int cur, int nxt) {
        // S^T = K @ Q^T, C-layout; K operands straight from global regs.
        f32x16 s0 = mfma32(kr[0], qf[0], zz);
        f32x16 s1 = mfma32(kr[1], qf[0], zz);
#pragma unroll
        for (int ks = 1; ks < 4; ks++) {
            s0 = mfma32(kr[ks * 2 + 0], qf[ks], s0);
            s1 = mfma32(kr[ks * 2 + 1], qf[ks], s1);
        }
        if (t < 31) {
#pragma unroll
            for (int f = 0; f < 8; f++) kr[f] = ldK(f, t + 1);
        }

        // half 0: exp2 -> P frags (natural order, PI-matched) -> PV + row-sum
#pragma unroll
        for (int r = 0; r < 16; r++) s0[r] = __builtin_amdgcn_exp2f(s0[r]);
        {
            bf16x8 pf0, pf1;
#pragma unroll
            for (int u = 0; u < 8; u++) { pf0[u] = (bf16)s0[u]; pf1[u] = (bf16)s0[8 + u]; }
            o0   = mfma32(pf0, *(const bf16x8*)(&Vb[cur][0][lane][0]), o0);
            o1   = mfma32(pf0, *(const bf16x8*)(&Vb[cur][1][lane][0]), o1);
            lacc = mfma32(pf0, ones, lacc);
            o0   = mfma32(pf1, *(const bf16x8*)(&Vb[cur][2][lane][0]), o0);
            o1   = mfma32(pf1, *(const bf16x8*)(&Vb[cur][3][lane][0]), o1);
            lacc = mfma32(pf1, ones, lacc);
        }
        // half 1
#pragma unroll
        for (int r = 0; r < 16; r++) s1[r] = __builtin_amdgcn_exp2f(s1[r]);
        {
            bf16x8 pf2, pf3;
#pragma unroll
            for (int u = 0; u < 8; u++) { pf2[u] = (bf16)s1[u]; pf3[u] = (bf16)s1[8 + u]; }
            o0   = mfma32(pf2, *(const bf16x8*)(&Vb[cur][4][lane][0]), o0);
            o1   = mfma32(pf2, *(const bf16x8*)(&Vb[cur][5][lane][0]), o1);
            lacc = mfma32(pf2, ones, lacc);
            o0   = mfma32(pf3, *(const bf16x8*)(&Vb[cur][6][lane][0]), o0);
            o1   = mfma32(pf3, *(const bf16x8*)(&Vb[cur][7][lane][0]), o1);
            lacc = mfma32(pf3, ones, lacc);
        }

        if (t < 31) {
            // store tile t+1 (loaded 2 tiles ago), then refill with tile t+3
#pragma unroll
            for (int i = 0; i < 4; i++)
                *(bf16x8*)(&Vb[1 - cur][w * 4 + i][lane][0]) = vr[nxt][i];
            const int tn = (t + 3 < 32) ? t + 3 : 31;
#pragma unroll
            for (int i = 0; i < 4; i++) vr[nxt][i] = ldV(w * 4 + i, tn);
            __syncthreads();
        }
    };

    for (int tt = 0; tt < 16; tt++) {
        tile_body(2 * tt + 0, 0, 1);
        tile_body(2 * tt + 1, 1, 0);
    }

    // Epilogue: lacc rows carry this lane's q-row sums (all n-cols identical).
    const int b = bh >> 3, h = bh & 7;
#pragma unroll
    for (int r = 0; r < 16; r++) {
        const int rl = (r & 3) + 8 * (r >> 2) + 4 * hi;
        const float inv = 1.0f / lacc[r];
        const int m = b * L_ + qb + rl;
        const int c0 = h * HD_ + l31;
        Op[((size_t)(c0 >> 3) * M_ + m) * 8 + (c0 & 7)] = (bf16)(o0[r] * inv);
        const int c1 = c0 + 32;
        Op[((size_t)(c1 >> 3) * M_ + m) * 8 + (c1 & 7)] = (bf16)(o1[r] * inv);
    }
}

extern "C" void kernel_launch(void* const* d_in, const int* in_sizes, int n_in,
                              void* d_out, int out_size, void* d_ws, size_t ws_size,
                              hipStream_t stream)
{
    (void)in_sizes; (void)n_in; (void)out_size; (void)ws_size;
    const float* q  = (const float*)d_in[0];
    const float* k  = (const float*)d_in[1];
    const float* v  = (const float*)d_in[2];
    const float* Wq = (const float*)d_in[3];
    const float* bq = (const float*)d_in[4];
    const float* Wk = (const float*)d_in[5];
    const float* bk = (const float*)d_in[6];
    const float* Wv = (const float*)d_in[7];
    const float* bv = (const float*)d_in[8];
    const float* Wo = (const float*)d_in[9];
    const float* bo = (const float*)d_in[10];
    float* out = (float*)d_out;

    // ws (18 MB): Vp @0, Opb @8M, Wp @16M.  No P0/P1/P2 -- q/k/v transpose
    // is fused into proj_qkv, so the merged z3 path ALWAYS fits.
    // d_out (16 MB): qh @0, Kp @8M -- dead before the final projection,
    // which overwrites d_out with the fp32 result.
    char* ws = (char*)d_ws;
    const size_t MB = 1024 * 1024;
    bf16* Vp  = (bf16*)(ws);
    bf16* Opb = (bf16*)(ws + 8 * MB);
    bf16* Wp  = (bf16*)(ws + 16 * MB);
    bf16* qh  = (bf16*)(d_out);
    bf16* Kp  = (bf16*)((char*)d_out + 8 * MB);

    bf16* Wqp = Wp;
    bf16* Wkp = Wp + (size_t)64 * 512 * 8;
    bf16* Wvp = Wp + (size_t)2 * 64 * 512 * 8;
    bf16* Wop = Wp + (size_t)3 * 64 * 512 * 8;

    const float SCALE_LOG2E = 0.06377946282349575f;  // (1/sqrt(512))*log2(e)

    pack_w<<<dim3(8, 8, 4), dim3(256), 0, stream>>>(Wq, Wk, Wv, Wo, Wp);

    PJob jq{nullptr, q, Wqp, bq, qh, SCALE_LOG2E, 0};
    PJob jk{nullptr, k, Wkp, bk, Kp, 1.0f, 1};
    PJob jv{nullptr, v, Wvp, bv, Vp, 1.0f, 3};
    proj_qkv_kernel<<<dim3(64, 4, 3), dim3(256), 0, stream>>>(jq, jk, jv);

    attn_kernel<<<dim3(32, 32), dim3(128), 0, stream>>>(qh, Kp, Vp, Opb);

    PJob jo{Opb, nullptr, Wop, bo, out, 1.0f, 2};
    proj_kernel<<<dim3(64, 4, 1), dim3(256), 0, stream>>>(jo, jo, jo);
}